// Round 1
// baseline (855.183 us; speedup 1.0000x reference)
//
#include <hip/hip_runtime.h>
#include <cstdint>

// ---------------- CSR build ----------------

__global__ void zero_ints(int* __restrict__ p, int n) {
    int i = blockIdx.x * blockDim.x + threadIdx.x;
    if (i < n) p[i] = 0;
}

__global__ void count_edges(const int* __restrict__ dst, int* __restrict__ cnt, int ne) {
    int e = blockIdx.x * blockDim.x + threadIdx.x;
    if (e < ne) atomicAdd(&cnt[dst[e]], 1);
}

// per-block inclusive scan (256/block), emits per-element inclusive + block sums
__global__ void scan_blocks(const int* __restrict__ cnt, int* __restrict__ inc,
                            int* __restrict__ blockSums, int n) {
    __shared__ int tmp[256];
    int i = blockIdx.x * 256 + threadIdx.x;
    tmp[threadIdx.x] = (i < n) ? cnt[i] : 0;
    __syncthreads();
    for (int off = 1; off < 256; off <<= 1) {
        int t = (threadIdx.x >= (unsigned)off) ? tmp[threadIdx.x - off] : 0;
        __syncthreads();
        tmp[threadIdx.x] += t;
        __syncthreads();
    }
    if (i < n) inc[i] = tmp[threadIdx.x];
    if (threadIdx.x == 255) blockSums[blockIdx.x] = tmp[255];
}

// single-block exclusive scan of block sums (nb <= 512)
__global__ void scan_partials(int* __restrict__ blockSums, int nb) {
    __shared__ int tmp[512];
    tmp[threadIdx.x] = (threadIdx.x < (unsigned)nb) ? blockSums[threadIdx.x] : 0;
    __syncthreads();
    for (int off = 1; off < 512; off <<= 1) {
        int t = (threadIdx.x >= (unsigned)off) ? tmp[threadIdx.x - off] : 0;
        __syncthreads();
        tmp[threadIdx.x] += t;
        __syncthreads();
    }
    int excl = (threadIdx.x == 0) ? 0 : tmp[threadIdx.x - 1];
    if (threadIdx.x < (unsigned)nb) blockSums[threadIdx.x] = excl;
}

__global__ void finalize_offsets(const int* __restrict__ cnt, const int* __restrict__ inc,
                                 const int* __restrict__ blockSums, int* __restrict__ offs,
                                 int* __restrict__ cursor, float* __restrict__ dinv, int n) {
    int i = blockIdx.x * 256 + threadIdx.x;
    if (i >= n) return;
    int inclusive = inc[i] + blockSums[blockIdx.x];
    int exclusive = inclusive - cnt[i];
    offs[i]   = exclusive;
    cursor[i] = exclusive;
    if (i == n - 1) offs[n] = inclusive;
    dinv[i] = rsqrtf((float)(cnt[i] + 1));  // deg = indeg + 1 (self loop), always > 0
}

__global__ void fill_csr(const int* __restrict__ src, const int* __restrict__ dst,
                         int* __restrict__ cursor, int* __restrict__ csr, int ne) {
    int e = blockIdx.x * blockDim.x + threadIdx.x;
    if (e < ne) {
        int p = atomicAdd(&cursor[dst[e]], 1);
        csr[p] = src[e];
    }
}

// ---------------- GCN layer kernels ----------------

// s[n,m] = (x @ W)[n,m] * dinv[n]; W (K x M row-major) staged in LDS.
template <int K, int M>
__global__ void gemm_scale(const float* __restrict__ x, const float* __restrict__ W,
                           const float* __restrict__ dinv, float* __restrict__ s, int n) {
    __shared__ float Ws[K * M];
    for (int i = threadIdx.x; i < K * M; i += blockDim.x) Ws[i] = W[i];
    __syncthreads();
    int g = blockIdx.x * blockDim.x + threadIdx.x;
    int node = g / M;
    int m = g - node * M;
    if (node >= n) return;
    const float* xr = x + (long long)node * K;
    float acc = 0.0f;
#pragma unroll
    for (int k = 0; k < K; ++k) acc = fmaf(xr[k], Ws[k * M + m], acc);
    s[(long long)node * M + m] = acc * dinv[node];
}

// out[d,f] = relu( dinv[d] * (s[d,f] + sum_{src in csr[d]} s[src,f]) + b[f] )
// TPN threads cooperate per node (TPN >= M), block handles blockDim/TPN nodes.
template <int M, int TPN>
__global__ void aggregate(const float* __restrict__ s, const int* __restrict__ offs,
                          const int* __restrict__ csr, const float* __restrict__ dinv,
                          const float* __restrict__ b, float* __restrict__ out, int n) {
    int f = threadIdx.x % TPN;
    int node = blockIdx.x * (blockDim.x / TPN) + threadIdx.x / TPN;
    if (node >= n) return;
    bool active = (f < M);
    float acc = active ? s[(long long)node * M + f] : 0.0f;
    int e0 = offs[node], e1 = offs[node + 1];
    for (int e = e0; e < e1; ++e) {
        int sid = csr[e];
        if (active) acc += s[(long long)sid * M + f];
    }
    if (active) out[(long long)node * M + f] = fmaxf(dinv[node] * acc + b[f], 0.0f);
}

// ---------------- fused 3-layer MLP: 25 -> 25 -> 10 -> 1, relu each ----------------

__global__ void mlp3(const float* __restrict__ x,
                     const float* __restrict__ Wl1, const float* __restrict__ bl1,
                     const float* __restrict__ Wl2, const float* __restrict__ bl2,
                     const float* __restrict__ Wl3, const float* __restrict__ bl3,
                     float* __restrict__ out, int n) {
    __shared__ float W1s[25 * 25], W2s[25 * 10], W3s[10], b1s[25], b2s[10], b3s;
    for (int i = threadIdx.x; i < 625; i += blockDim.x) W1s[i] = Wl1[i];
    for (int i = threadIdx.x; i < 250; i += blockDim.x) W2s[i] = Wl2[i];
    if (threadIdx.x < 10) { W3s[threadIdx.x] = Wl3[threadIdx.x]; b2s[threadIdx.x] = bl2[threadIdx.x]; }
    if (threadIdx.x < 25) b1s[threadIdx.x] = bl1[threadIdx.x];
    if (threadIdx.x == 0) b3s = bl3[0];
    __syncthreads();
    int node = blockIdx.x * blockDim.x + threadIdx.x;
    if (node >= n) return;
    float xr[25];
#pragma unroll
    for (int k = 0; k < 25; ++k) xr[k] = x[(long long)node * 25 + k];
    float h1[25];
#pragma unroll
    for (int m = 0; m < 25; ++m) {
        float a = b1s[m];
#pragma unroll
        for (int k = 0; k < 25; ++k) a = fmaf(xr[k], W1s[k * 25 + m], a);
        h1[m] = fmaxf(a, 0.0f);
    }
    float h2[10];
#pragma unroll
    for (int m = 0; m < 10; ++m) {
        float a = b2s[m];
#pragma unroll
        for (int k = 0; k < 25; ++k) a = fmaf(h1[k], W2s[k * 10 + m], a);
        h2[m] = fmaxf(a, 0.0f);
    }
    float a = b3s;
#pragma unroll
    for (int k = 0; k < 10; ++k) a = fmaf(h2[k], W3s[k], a);
    out[node] = fmaxf(a, 0.0f);
}

// ---------------- launch ----------------

extern "C" void kernel_launch(void* const* d_in, const int* in_sizes, int n_in,
                              void* d_out, int out_size, void* d_ws, size_t ws_size,
                              hipStream_t stream) {
    const float* x0  = (const float*)d_in[0];
    const float* W1  = (const float*)d_in[1];
    const float* b1  = (const float*)d_in[2];
    const float* W2  = (const float*)d_in[3];
    const float* b2  = (const float*)d_in[4];
    const float* W3  = (const float*)d_in[5];
    const float* b3  = (const float*)d_in[6];
    const float* Wl1 = (const float*)d_in[7];
    const float* bl1 = (const float*)d_in[8];
    const float* Wl2 = (const float*)d_in[9];
    const float* bl2 = (const float*)d_in[10];
    const float* Wl3 = (const float*)d_in[11];
    const float* bl3 = (const float*)d_in[12];
    const int*   edge = (const int*)d_in[13];   // int32 (JAX x64 disabled), [2, E] flat

    int n  = in_sizes[0] / 64;      // 100000
    int ne = in_sizes[13] / 2;      // 1000000
    const int* esrc = edge;
    const int* edst = edge + ne;

    // workspace carve-out (256B aligned)
    char* ws = (char*)d_ws;
    auto alloc = [&](size_t bytes) {
        char* p = ws;
        ws += (bytes + 255) & ~(size_t)255;
        return p;
    };
    int*   cnt       = (int*)alloc((size_t)n * 4);
    int*   offs      = (int*)alloc((size_t)(n + 1) * 4);
    int*   cursor    = (int*)alloc((size_t)n * 4);
    int*   inc       = (int*)alloc((size_t)n * 4);
    int*   blockSums = (int*)alloc(512 * 4);
    int*   csr       = (int*)alloc((size_t)ne * 4);
    float* dinv      = (float*)alloc((size_t)n * 4);
    float* bufA      = (float*)alloc((size_t)n * 100 * 4);
    float* bufB      = (float*)alloc((size_t)n * 100 * 4);
    (void)ws_size; (void)n_in; (void)out_size;

    int nb  = (n + 255) / 256;     // 391 (must be <= 512 for scan_partials)
    int neb = (ne + 255) / 256;

    // CSR + dinv (recomputed every call; ws is re-poisoned by harness)
    zero_ints<<<nb, 256, 0, stream>>>(cnt, n);
    count_edges<<<neb, 256, 0, stream>>>(edst, cnt, ne);
    scan_blocks<<<nb, 256, 0, stream>>>(cnt, inc, blockSums, n);
    scan_partials<<<1, 512, 0, stream>>>(blockSums, nb);
    finalize_offsets<<<nb, 256, 0, stream>>>(cnt, inc, blockSums, offs, cursor, dinv, n);
    fill_csr<<<neb, 256, 0, stream>>>(esrc, edst, cursor, csr, ne);

    // GCN layer 1: 64 -> 100
    gemm_scale<64, 100><<<((long long)n * 100 + 255) / 256, 256, 0, stream>>>(x0, W1, dinv, bufA, n);
    aggregate<100, 128><<<(n + 1) / 2, 256, 0, stream>>>(bufA, offs, csr, dinv, b1, bufB, n);
    // GCN layer 2: 100 -> 50
    gemm_scale<100, 50><<<((long long)n * 50 + 255) / 256, 256, 0, stream>>>(bufB, W2, dinv, bufA, n);
    aggregate<50, 64><<<(n + 3) / 4, 256, 0, stream>>>(bufA, offs, csr, dinv, b2, bufB, n);
    // GCN layer 3: 50 -> 25
    gemm_scale<50, 25><<<((long long)n * 25 + 255) / 256, 256, 0, stream>>>(bufB, W3, dinv, bufA, n);
    aggregate<25, 32><<<(n + 7) / 8, 256, 0, stream>>>(bufA, offs, csr, dinv, b3, bufB, n);

    // fused MLP head
    mlp3<<<nb, 256, 0, stream>>>(bufB, Wl1, bl1, Wl2, bl2, Wl3, bl3, (float*)d_out, n);
}

// Round 2
// 627.779 us; speedup vs baseline: 1.3622x; 1.3622x over previous
//
#include <hip/hip_runtime.h>
#include <cstdint>

// ---------------- CSR build ----------------

__global__ void zero_ints(int* __restrict__ p, int n) {
    int i = blockIdx.x * blockDim.x + threadIdx.x;
    if (i < n) p[i] = 0;
}

__global__ void count_edges(const int* __restrict__ dst, int* __restrict__ cnt, int ne) {
    int e = blockIdx.x * blockDim.x + threadIdx.x;
    if (e < ne) atomicAdd(&cnt[dst[e]], 1);
}

__global__ void scan_blocks(const int* __restrict__ cnt, int* __restrict__ inc,
                            int* __restrict__ blockSums, int n) {
    __shared__ int tmp[256];
    int i = blockIdx.x * 256 + threadIdx.x;
    tmp[threadIdx.x] = (i < n) ? cnt[i] : 0;
    __syncthreads();
    for (int off = 1; off < 256; off <<= 1) {
        int t = (threadIdx.x >= (unsigned)off) ? tmp[threadIdx.x - off] : 0;
        __syncthreads();
        tmp[threadIdx.x] += t;
        __syncthreads();
    }
    if (i < n) inc[i] = tmp[threadIdx.x];
    if (threadIdx.x == 255) blockSums[blockIdx.x] = tmp[255];
}

__global__ void scan_partials(int* __restrict__ blockSums, int nb) {
    __shared__ int tmp[512];
    tmp[threadIdx.x] = (threadIdx.x < (unsigned)nb) ? blockSums[threadIdx.x] : 0;
    __syncthreads();
    for (int off = 1; off < 512; off <<= 1) {
        int t = (threadIdx.x >= (unsigned)off) ? tmp[threadIdx.x - off] : 0;
        __syncthreads();
        tmp[threadIdx.x] += t;
        __syncthreads();
    }
    int excl = (threadIdx.x == 0) ? 0 : tmp[threadIdx.x - 1];
    if (threadIdx.x < (unsigned)nb) blockSums[threadIdx.x] = excl;
}

__global__ void finalize_offsets(const int* __restrict__ cnt, const int* __restrict__ inc,
                                 const int* __restrict__ blockSums, int* __restrict__ offs,
                                 int* __restrict__ cursor, float* __restrict__ dinv, int n) {
    int i = blockIdx.x * 256 + threadIdx.x;
    if (i >= n) return;
    int inclusive = inc[i] + blockSums[blockIdx.x];
    int exclusive = inclusive - cnt[i];
    offs[i]   = exclusive;
    cursor[i] = exclusive;
    if (i == n - 1) offs[n] = inclusive;
    dinv[i] = rsqrtf((float)(cnt[i] + 1));  // deg = indeg + 1 (self loop)
}

__global__ void fill_csr(const int* __restrict__ src, const int* __restrict__ dst,
                         int* __restrict__ cursor, int* __restrict__ csr, int ne) {
    int e = blockIdx.x * blockDim.x + threadIdx.x;
    if (e < ne) {
        int p = atomicAdd(&cursor[dst[e]], 1);
        csr[p] = src[e];
    }
}

// ---------------- aggregation ----------------
// TPN lanes per node. SCALE_SRC: multiply gathered rows by dinv[src] (layer-1,
// aggregating raw input). RELU_BIAS: out = relu(dinv[d]*acc + b[f]); else
// out = dinv[d]*acc (bias/relu deferred to the following GEMM).
// 4-way unrolled edge loop: 4 independent row-loads in flight per wave.
template <int M, int TPN, bool SCALE_SRC, bool RELU_BIAS>
__global__ void aggregate(const float* __restrict__ s, const int* __restrict__ offs,
                          const int* __restrict__ csr, const float* __restrict__ dinv,
                          const float* __restrict__ b, float* __restrict__ out, int n) {
    int f = threadIdx.x % TPN;
    int node = blockIdx.x * (blockDim.x / TPN) + threadIdx.x / TPN;
    if (node >= n) return;
    bool active = (TPN == M) || (f < M);
    float dv = dinv[node];

    float self_v = active ? s[(long long)node * M + f] : 0.0f;
    float acc = SCALE_SRC ? self_v * dv : self_v;

    int e0 = offs[node], e1 = offs[node + 1];
    float a0 = 0.0f, a1 = 0.0f, a2 = 0.0f, a3 = 0.0f;
    int e = e0;
    for (; e + 4 <= e1; e += 4) {
        int s0 = csr[e], s1 = csr[e + 1], s2 = csr[e + 2], s3 = csr[e + 3];
        float v0 = 0.f, v1 = 0.f, v2 = 0.f, v3 = 0.f;
        if (active) {
            v0 = s[(long long)s0 * M + f];
            v1 = s[(long long)s1 * M + f];
            v2 = s[(long long)s2 * M + f];
            v3 = s[(long long)s3 * M + f];
        }
        if (SCALE_SRC) {
            v0 *= dinv[s0]; v1 *= dinv[s1]; v2 *= dinv[s2]; v3 *= dinv[s3];
        }
        a0 += v0; a1 += v1; a2 += v2; a3 += v3;
    }
    for (; e < e1; ++e) {
        int sid = csr[e];
        float v = active ? s[(long long)sid * M + f] : 0.0f;
        if (SCALE_SRC) v *= dinv[sid];
        a0 += v;
    }
    acc += (a0 + a1) + (a2 + a3);

    if (active) {
        float r = dv * acc;
        if (RELU_BIAS) r = fmaxf(r + b[f], 0.0f);
        out[(long long)node * M + f] = r;
    }
}

// ---------------- GEMM (one thread per output element, W in LDS) ----------------
// SCALE:     out = (x@W)[n,m] * dinv[n]          (pre-scale for next aggregate)
// BIAS_RELU: out = relu((x@W)[n,m] + b[m])
template <int K, int M, bool SCALE, bool BIAS_RELU>
__global__ void gemm_fused(const float* __restrict__ x, const float* __restrict__ W,
                           const float* __restrict__ dinv, const float* __restrict__ b,
                           float* __restrict__ out, int n) {
    __shared__ float Ws[K * M];
    for (int i = threadIdx.x; i < K * M; i += blockDim.x) Ws[i] = W[i];
    __syncthreads();
    int g = blockIdx.x * blockDim.x + threadIdx.x;
    int node = g / M;
    int m = g - node * M;
    if (node >= n) return;
    const float* xr = x + (long long)node * K;
    float acc = 0.0f;
#pragma unroll
    for (int k = 0; k < K; ++k) acc = fmaf(xr[k], Ws[k * M + m], acc);
    if (SCALE) acc *= dinv[node];
    if (BIAS_RELU) acc = fmaxf(acc + b[m], 0.0f);
    out[(long long)node * M + m] = acc;
}

// ---------------- fused 3-layer MLP: 25 -> 25 -> 10 -> 1, relu each ----------------

__global__ void mlp3(const float* __restrict__ x,
                     const float* __restrict__ Wl1, const float* __restrict__ bl1,
                     const float* __restrict__ Wl2, const float* __restrict__ bl2,
                     const float* __restrict__ Wl3, const float* __restrict__ bl3,
                     float* __restrict__ out, int n) {
    __shared__ float W1s[25 * 25], W2s[25 * 10], W3s[10], b1s[25], b2s[10], b3s;
    for (int i = threadIdx.x; i < 625; i += blockDim.x) W1s[i] = Wl1[i];
    for (int i = threadIdx.x; i < 250; i += blockDim.x) W2s[i] = Wl2[i];
    if (threadIdx.x < 10) { W3s[threadIdx.x] = Wl3[threadIdx.x]; b2s[threadIdx.x] = bl2[threadIdx.x]; }
    if (threadIdx.x < 25) b1s[threadIdx.x] = bl1[threadIdx.x];
    if (threadIdx.x == 0) b3s = bl3[0];
    __syncthreads();
    int node = blockIdx.x * blockDim.x + threadIdx.x;
    if (node >= n) return;
    float xr[25];
#pragma unroll
    for (int k = 0; k < 25; ++k) xr[k] = x[(long long)node * 25 + k];
    float h1[25];
#pragma unroll
    for (int m = 0; m < 25; ++m) {
        float a = b1s[m];
#pragma unroll
        for (int k = 0; k < 25; ++k) a = fmaf(xr[k], W1s[k * 25 + m], a);
        h1[m] = fmaxf(a, 0.0f);
    }
    float h2[10];
#pragma unroll
    for (int m = 0; m < 10; ++m) {
        float a = b2s[m];
#pragma unroll
        for (int k = 0; k < 25; ++k) a = fmaf(h1[k], W2s[k * 10 + m], a);
        h2[m] = fmaxf(a, 0.0f);
    }
    float a = b3s;
#pragma unroll
    for (int k = 0; k < 10; ++k) a = fmaf(h2[k], W3s[k], a);
    out[node] = fmaxf(a, 0.0f);
}

// ---------------- launch ----------------

extern "C" void kernel_launch(void* const* d_in, const int* in_sizes, int n_in,
                              void* d_out, int out_size, void* d_ws, size_t ws_size,
                              hipStream_t stream) {
    const float* x0  = (const float*)d_in[0];
    const float* W1  = (const float*)d_in[1];
    const float* b1  = (const float*)d_in[2];
    const float* W2  = (const float*)d_in[3];
    const float* b2  = (const float*)d_in[4];
    const float* W3  = (const float*)d_in[5];
    const float* b3  = (const float*)d_in[6];
    const float* Wl1 = (const float*)d_in[7];
    const float* bl1 = (const float*)d_in[8];
    const float* Wl2 = (const float*)d_in[9];
    const float* bl2 = (const float*)d_in[10];
    const float* Wl3 = (const float*)d_in[11];
    const float* bl3 = (const float*)d_in[12];
    const int*   edge = (const int*)d_in[13];

    int n  = in_sizes[0] / 64;      // 100000
    int ne = in_sizes[13] / 2;      // 1000000
    const int* esrc = edge;
    const int* edst = edge + ne;

    char* ws = (char*)d_ws;
    auto alloc = [&](size_t bytes) {
        char* p = ws;
        ws += (bytes + 255) & ~(size_t)255;
        return p;
    };
    int*   cnt       = (int*)alloc((size_t)n * 4);
    int*   offs      = (int*)alloc((size_t)(n + 1) * 4);
    int*   cursor    = (int*)alloc((size_t)n * 4);
    int*   inc       = (int*)alloc((size_t)n * 4);
    int*   blockSums = (int*)alloc(512 * 4);
    int*   csr       = (int*)alloc((size_t)ne * 4);
    float* dinv      = (float*)alloc((size_t)n * 4);
    float* bufA      = (float*)alloc((size_t)n * 100 * 4);
    float* bufB      = (float*)alloc((size_t)n * 100 * 4);
    (void)ws_size; (void)n_in; (void)out_size;

    int nb  = (n + 255) / 256;
    int neb = (ne + 255) / 256;

    // CSR + dinv
    zero_ints<<<nb, 256, 0, stream>>>(cnt, n);
    count_edges<<<neb, 256, 0, stream>>>(edst, cnt, ne);
    scan_blocks<<<nb, 256, 0, stream>>>(cnt, inc, blockSums, n);
    scan_partials<<<1, 512, 0, stream>>>(blockSums, nb);
    finalize_offsets<<<nb, 256, 0, stream>>>(cnt, inc, blockSums, offs, cursor, dinv, n);
    fill_csr<<<neb, 256, 0, stream>>>(esrc, edst, cursor, csr, ne);

    // Layer 1 (aggregate-first: Â(XW) = (ÂX)W):
    //   bufA = dinv[d]*(x0[d]*dinv[d] + sum x0[src]*dinv[src])   [n,64]
    //   bufB = relu(bufA @ W1 + b1)                              [n,100]
    aggregate<64, 64, true, false><<<(n + 3) / 4, 256, 0, stream>>>(
        x0, offs, csr, dinv, nullptr, bufA, n);
    gemm_fused<64, 100, false, true><<<((long long)n * 100 + 255) / 256, 256, 0, stream>>>(
        bufA, W1, dinv, b1, bufB, n);

    // Layer 2: transform-then-aggregate (out dim 50 < in dim 100)
    gemm_fused<100, 50, true, false><<<((long long)n * 50 + 255) / 256, 256, 0, stream>>>(
        bufB, W2, dinv, nullptr, bufA, n);
    aggregate<50, 64, false, true><<<(n + 3) / 4, 256, 0, stream>>>(
        bufA, offs, csr, dinv, b2, bufB, n);

    // Layer 3: 50 -> 25
    gemm_fused<50, 25, true, false><<<((long long)n * 25 + 255) / 256, 256, 0, stream>>>(
        bufB, W3, dinv, nullptr, bufA, n);
    aggregate<25, 32, false, true><<<(n + 7) / 8, 256, 0, stream>>>(
        bufA, offs, csr, dinv, b3, bufB, n);

    // fused MLP head
    mlp3<<<nb, 256, 0, stream>>>(bufB, Wl1, bl1, Wl2, bl2, Wl3, bl3, (float*)d_out, n);
}

// Round 3
// 468.590 us; speedup vs baseline: 1.8250x; 1.3397x over previous
//
#include <hip/hip_runtime.h>
#include <cstdint>

// ---------------- CSR build ----------------

__global__ void zero_ints(int* __restrict__ p, int n) {
    int i = blockIdx.x * blockDim.x + threadIdx.x;
    if (i < n) p[i] = 0;
}

__global__ void count_edges(const int* __restrict__ dst, int* __restrict__ cnt, int ne) {
    int e = blockIdx.x * blockDim.x + threadIdx.x;
    if (e < ne) atomicAdd(&cnt[dst[e]], 1);
}

__global__ void scan_blocks(const int* __restrict__ cnt, int* __restrict__ inc,
                            int* __restrict__ blockSums, int n) {
    __shared__ int tmp[256];
    int i = blockIdx.x * 256 + threadIdx.x;
    tmp[threadIdx.x] = (i < n) ? cnt[i] : 0;
    __syncthreads();
    for (int off = 1; off < 256; off <<= 1) {
        int t = (threadIdx.x >= (unsigned)off) ? tmp[threadIdx.x - off] : 0;
        __syncthreads();
        tmp[threadIdx.x] += t;
        __syncthreads();
    }
    if (i < n) inc[i] = tmp[threadIdx.x];
    if (threadIdx.x == 255) blockSums[blockIdx.x] = tmp[255];
}

__global__ void scan_partials(int* __restrict__ blockSums, int nb) {
    __shared__ int tmp[512];
    tmp[threadIdx.x] = (threadIdx.x < (unsigned)nb) ? blockSums[threadIdx.x] : 0;
    __syncthreads();
    for (int off = 1; off < 512; off <<= 1) {
        int t = (threadIdx.x >= (unsigned)off) ? tmp[threadIdx.x - off] : 0;
        __syncthreads();
        tmp[threadIdx.x] += t;
        __syncthreads();
    }
    int excl = (threadIdx.x == 0) ? 0 : tmp[threadIdx.x - 1];
    if (threadIdx.x < (unsigned)nb) blockSums[threadIdx.x] = excl;
}

__global__ void finalize_offsets(const int* __restrict__ cnt, const int* __restrict__ inc,
                                 const int* __restrict__ blockSums, int* __restrict__ offs,
                                 int* __restrict__ cursor, float* __restrict__ dinv, int n) {
    int i = blockIdx.x * 256 + threadIdx.x;
    if (i >= n) return;
    int inclusive = inc[i] + blockSums[blockIdx.x];
    int exclusive = inclusive - cnt[i];
    offs[i]   = exclusive;
    cursor[i] = exclusive;
    if (i == n - 1) offs[n] = inclusive;
    dinv[i] = rsqrtf((float)(cnt[i] + 1));  // deg = indeg + 1 (self loop)
}

__global__ void fill_csr(const int* __restrict__ src, const int* __restrict__ dst,
                         int* __restrict__ cursor, int* __restrict__ csr, int ne) {
    int e = blockIdx.x * blockDim.x + threadIdx.x;
    if (e < ne) {
        int p = atomicAdd(&cursor[dst[e]], 1);
        csr[p] = src[e];
    }
}

// ---------------- aggregation (unchanged from R1) ----------------
template <int M, int TPN, bool SCALE_SRC, bool RELU_BIAS>
__global__ void aggregate(const float* __restrict__ s, const int* __restrict__ offs,
                          const int* __restrict__ csr, const float* __restrict__ dinv,
                          const float* __restrict__ b, float* __restrict__ out, int n) {
    int f = threadIdx.x % TPN;
    int node = blockIdx.x * (blockDim.x / TPN) + threadIdx.x / TPN;
    if (node >= n) return;
    bool active = (TPN == M) || (f < M);
    float dv = dinv[node];

    float self_v = active ? s[(long long)node * M + f] : 0.0f;
    float acc = SCALE_SRC ? self_v * dv : self_v;

    int e0 = offs[node], e1 = offs[node + 1];
    float a0 = 0.0f, a1 = 0.0f, a2 = 0.0f, a3 = 0.0f;
    int e = e0;
    for (; e + 4 <= e1; e += 4) {
        int s0 = csr[e], s1 = csr[e + 1], s2 = csr[e + 2], s3 = csr[e + 3];
        float v0 = 0.f, v1 = 0.f, v2 = 0.f, v3 = 0.f;
        if (active) {
            v0 = s[(long long)s0 * M + f];
            v1 = s[(long long)s1 * M + f];
            v2 = s[(long long)s2 * M + f];
            v3 = s[(long long)s3 * M + f];
        }
        if (SCALE_SRC) {
            v0 *= dinv[s0]; v1 *= dinv[s1]; v2 *= dinv[s2]; v3 *= dinv[s3];
        }
        a0 += v0; a1 += v1; a2 += v2; a3 += v3;
    }
    for (; e < e1; ++e) {
        int sid = csr[e];
        float v = active ? s[(long long)sid * M + f] : 0.0f;
        if (SCALE_SRC) v *= dinv[sid];
        a0 += v;
    }
    acc += (a0 + a1) + (a2 + a3);

    if (active) {
        float r = dv * acc;
        if (RELU_BIAS) r = fmaxf(r + b[f], 0.0f);
        out[(long long)node * M + f] = r;
    }
}

// ---------------- register-tiled GEMM ----------------
// Block: 256 threads, tile = NT nodes x M outputs.
// LDS: Xs transposed [K][NTp] (4 consecutive nodes at fixed k -> ds_read_b128),
//      Ws [K][Mp] padded to multiple-of-4 cols (b128 on m-quads).
// Each thread: 4-node x 4-m micro-tile; per k: 2x b128 LDS reads + 16 FMA.
template <int K, int M, int NT, bool SCALE, bool BIAS_RELU>
__global__ __launch_bounds__(256) void gemm_tiled(
    const float* __restrict__ x, const float* __restrict__ W,
    const float* __restrict__ dinv, const float* __restrict__ b,
    float* __restrict__ out, int n) {
    static_assert(NT % 4 == 0 && K % 2 == 0, "");
    constexpr int Mp  = (M + 3) & ~3;
    constexpr int MQ  = Mp / 4;
    constexpr int NTp = (NT + 4) & ~3;   // padded, multiple of 4, > NT
    constexpr int NTILES = (NT / 4) * MQ;
    static_assert(NTILES <= 256, "");

    __shared__ float Xs[K * NTp];
    __shared__ float Ws[K * Mp];

    // stage W (zero-pad cols)
    for (int i = threadIdx.x; i < K * Mp; i += 256) {
        int k = i / Mp, m = i - k * Mp;
        Ws[i] = (m < M) ? W[k * M + m] : 0.0f;
    }
    // stage X transposed (float2 granularity; K is even)
    int nodeBase = blockIdx.x * NT;
    for (int t = threadIdx.x; t < NT * (K / 2); t += 256) {
        int node = t / (K / 2);
        int k2 = t - node * (K / 2);
        int gn = nodeBase + node;
        float2 v = make_float2(0.0f, 0.0f);
        if (gn < n) v = *(const float2*)&x[(long long)gn * K + k2 * 2];
        Xs[(k2 * 2)     * NTp + node] = v.x;
        Xs[(k2 * 2 + 1) * NTp + node] = v.y;
    }
    __syncthreads();

    int t = threadIdx.x;
    if (t >= NTILES) return;
    int ng = t / MQ, mq = t - ng * MQ;
    int n0 = ng * 4;
    int m0 = mq * 4;

    float acc[4][4];
#pragma unroll
    for (int j = 0; j < 4; ++j)
#pragma unroll
        for (int i = 0; i < 4; ++i) acc[j][i] = 0.0f;

#pragma unroll 2
    for (int k = 0; k < K; ++k) {
        float4 xv = *(const float4*)&Xs[k * NTp + n0];
        float4 wv = *(const float4*)&Ws[k * Mp + m0];
        acc[0][0] = fmaf(xv.x, wv.x, acc[0][0]);
        acc[0][1] = fmaf(xv.x, wv.y, acc[0][1]);
        acc[0][2] = fmaf(xv.x, wv.z, acc[0][2]);
        acc[0][3] = fmaf(xv.x, wv.w, acc[0][3]);
        acc[1][0] = fmaf(xv.y, wv.x, acc[1][0]);
        acc[1][1] = fmaf(xv.y, wv.y, acc[1][1]);
        acc[1][2] = fmaf(xv.y, wv.z, acc[1][2]);
        acc[1][3] = fmaf(xv.y, wv.w, acc[1][3]);
        acc[2][0] = fmaf(xv.z, wv.x, acc[2][0]);
        acc[2][1] = fmaf(xv.z, wv.y, acc[2][1]);
        acc[2][2] = fmaf(xv.z, wv.z, acc[2][2]);
        acc[2][3] = fmaf(xv.z, wv.w, acc[2][3]);
        acc[3][0] = fmaf(xv.w, wv.x, acc[3][0]);
        acc[3][1] = fmaf(xv.w, wv.y, acc[3][1]);
        acc[3][2] = fmaf(xv.w, wv.z, acc[3][2]);
        acc[3][3] = fmaf(xv.w, wv.w, acc[3][3]);
    }

#pragma unroll
    for (int j = 0; j < 4; ++j) {
        int nd = nodeBase + n0 + j;
        if (nd >= n) continue;
        float dv = SCALE ? dinv[nd] : 1.0f;
#pragma unroll
        for (int i = 0; i < 4; ++i) {
            int m = m0 + i;
            if (m < M) {
                float r = acc[j][i];
                if (SCALE) r *= dv;
                if (BIAS_RELU) r = fmaxf(r + b[m], 0.0f);
                out[(long long)nd * M + m] = r;
            }
        }
    }
}

// ---------------- fused 3-layer MLP: 25 -> 25 -> 10 -> 1, relu each ----------------

__global__ void mlp3(const float* __restrict__ x,
                     const float* __restrict__ Wl1, const float* __restrict__ bl1,
                     const float* __restrict__ Wl2, const float* __restrict__ bl2,
                     const float* __restrict__ Wl3, const float* __restrict__ bl3,
                     float* __restrict__ out, int n) {
    __shared__ float W1s[25 * 25], W2s[25 * 10], W3s[10], b1s[25], b2s[10], b3s;
    for (int i = threadIdx.x; i < 625; i += blockDim.x) W1s[i] = Wl1[i];
    for (int i = threadIdx.x; i < 250; i += blockDim.x) W2s[i] = Wl2[i];
    if (threadIdx.x < 10) { W3s[threadIdx.x] = Wl3[threadIdx.x]; b2s[threadIdx.x] = bl2[threadIdx.x]; }
    if (threadIdx.x < 25) b1s[threadIdx.x] = bl1[threadIdx.x];
    if (threadIdx.x == 0) b3s = bl3[0];
    __syncthreads();
    int node = blockIdx.x * blockDim.x + threadIdx.x;
    if (node >= n) return;
    float xr[25];
#pragma unroll
    for (int k = 0; k < 25; ++k) xr[k] = x[(long long)node * 25 + k];
    float h1[25];
#pragma unroll
    for (int m = 0; m < 25; ++m) {
        float a = b1s[m];
#pragma unroll
        for (int k = 0; k < 25; ++k) a = fmaf(xr[k], W1s[k * 25 + m], a);
        h1[m] = fmaxf(a, 0.0f);
    }
    float h2[10];
#pragma unroll
    for (int m = 0; m < 10; ++m) {
        float a = b2s[m];
#pragma unroll
        for (int k = 0; k < 25; ++k) a = fmaf(h1[k], W2s[k * 10 + m], a);
        h2[m] = fmaxf(a, 0.0f);
    }
    float a = b3s;
#pragma unroll
    for (int k = 0; k < 10; ++k) a = fmaf(h2[k], W3s[k], a);
    out[node] = fmaxf(a, 0.0f);
}

// ---------------- launch ----------------

extern "C" void kernel_launch(void* const* d_in, const int* in_sizes, int n_in,
                              void* d_out, int out_size, void* d_ws, size_t ws_size,
                              hipStream_t stream) {
    const float* x0  = (const float*)d_in[0];
    const float* W1  = (const float*)d_in[1];
    const float* b1  = (const float*)d_in[2];
    const float* W2  = (const float*)d_in[3];
    const float* b2  = (const float*)d_in[4];
    const float* W3  = (const float*)d_in[5];
    const float* b3  = (const float*)d_in[6];
    const float* Wl1 = (const float*)d_in[7];
    const float* bl1 = (const float*)d_in[8];
    const float* Wl2 = (const float*)d_in[9];
    const float* bl2 = (const float*)d_in[10];
    const float* Wl3 = (const float*)d_in[11];
    const float* bl3 = (const float*)d_in[12];
    const int*   edge = (const int*)d_in[13];

    int n  = in_sizes[0] / 64;      // 100000
    int ne = in_sizes[13] / 2;      // 1000000
    const int* esrc = edge;
    const int* edst = edge + ne;

    char* ws = (char*)d_ws;
    auto alloc = [&](size_t bytes) {
        char* p = ws;
        ws += (bytes + 255) & ~(size_t)255;
        return p;
    };
    int*   cnt       = (int*)alloc((size_t)n * 4);
    int*   offs      = (int*)alloc((size_t)(n + 1) * 4);
    int*   cursor    = (int*)alloc((size_t)n * 4);
    int*   inc       = (int*)alloc((size_t)n * 4);
    int*   blockSums = (int*)alloc(512 * 4);
    int*   csr       = (int*)alloc((size_t)ne * 4);
    float* dinv      = (float*)alloc((size_t)n * 4);
    float* bufA      = (float*)alloc((size_t)n * 100 * 4);
    float* bufB      = (float*)alloc((size_t)n * 100 * 4);
    (void)ws_size; (void)n_in; (void)out_size;

    int nb  = (n + 255) / 256;
    int neb = (ne + 255) / 256;

    // CSR + dinv
    zero_ints<<<nb, 256, 0, stream>>>(cnt, n);
    count_edges<<<neb, 256, 0, stream>>>(edst, cnt, ne);
    scan_blocks<<<nb, 256, 0, stream>>>(cnt, inc, blockSums, n);
    scan_partials<<<1, 512, 0, stream>>>(blockSums, nb);
    finalize_offsets<<<nb, 256, 0, stream>>>(cnt, inc, blockSums, offs, cursor, dinv, n);
    fill_csr<<<neb, 256, 0, stream>>>(esrc, edst, cursor, csr, ne);

    // Layer 1 (aggregate-first): bufA = ÂX [n,64]; bufB = relu(bufA@W1+b1) [n,100]
    aggregate<64, 64, true, false><<<(n + 3) / 4, 256, 0, stream>>>(
        x0, offs, csr, dinv, nullptr, bufA, n);
    gemm_tiled<64, 100, 40, false, true><<<(n + 39) / 40, 256, 0, stream>>>(
        bufA, W1, nullptr, b1, bufB, n);

    // Layer 2: transform-then-aggregate
    gemm_tiled<100, 50, 76, true, false><<<(n + 75) / 76, 256, 0, stream>>>(
        bufB, W2, dinv, nullptr, bufA, n);
    aggregate<50, 64, false, true><<<(n + 3) / 4, 256, 0, stream>>>(
        bufA, offs, csr, dinv, b2, bufB, n);

    // Layer 3: 50 -> 25
    gemm_tiled<50, 25, 144, true, false><<<(n + 143) / 144, 256, 0, stream>>>(
        bufB, W3, dinv, nullptr, bufA, n);
    aggregate<25, 32, false, true><<<(n + 7) / 8, 256, 0, stream>>>(
        bufA, offs, csr, dinv, b3, bufB, n);

    // fused MLP head
    mlp3<<<nb, 256, 0, stream>>>(bufB, Wl1, bl1, Wl2, bl2, Wl3, bl3, (float*)d_out, n);
}

// Round 4
// 442.747 us; speedup vs baseline: 1.9315x; 1.0584x over previous
//
#include <hip/hip_runtime.h>
#include <cstdint>

constexpr int BSHIFT = 9;               // 512 nodes per bucket
constexpr int NBUCK  = 256;             // covers up to 131072 nodes

// ---------------- CSR build ----------------

__global__ void zero_ints(int* __restrict__ p, int n) {
    int i = blockIdx.x * blockDim.x + threadIdx.x;
    if (i < n) p[i] = 0;
}

__global__ void count_edges(const int* __restrict__ dst, int* __restrict__ cnt, int ne) {
    int e = blockIdx.x * blockDim.x + threadIdx.x;
    if (e < ne) atomicAdd(&cnt[dst[e]], 1);
}

__global__ void scan_blocks(const int* __restrict__ cnt, int* __restrict__ inc,
                            int* __restrict__ blockSums, int n) {
    __shared__ int tmp[256];
    int i = blockIdx.x * 256 + threadIdx.x;
    tmp[threadIdx.x] = (i < n) ? cnt[i] : 0;
    __syncthreads();
    for (int off = 1; off < 256; off <<= 1) {
        int t = (threadIdx.x >= (unsigned)off) ? tmp[threadIdx.x - off] : 0;
        __syncthreads();
        tmp[threadIdx.x] += t;
        __syncthreads();
    }
    if (i < n) inc[i] = tmp[threadIdx.x];
    if (threadIdx.x == 255) blockSums[blockIdx.x] = tmp[255];
}

__global__ void scan_partials(int* __restrict__ blockSums, int nb) {
    __shared__ int tmp[512];
    tmp[threadIdx.x] = (threadIdx.x < (unsigned)nb) ? blockSums[threadIdx.x] : 0;
    __syncthreads();
    for (int off = 1; off < 512; off <<= 1) {
        int t = (threadIdx.x >= (unsigned)off) ? tmp[threadIdx.x - off] : 0;
        __syncthreads();
        tmp[threadIdx.x] += t;
        __syncthreads();
    }
    int excl = (threadIdx.x == 0) ? 0 : tmp[threadIdx.x - 1];
    if (threadIdx.x < (unsigned)nb) blockSums[threadIdx.x] = excl;
}

__global__ void finalize_offsets(const int* __restrict__ cnt, const int* __restrict__ inc,
                                 const int* __restrict__ blockSums, int* __restrict__ offs,
                                 int* __restrict__ cursor, int* __restrict__ bucketCursor,
                                 float* __restrict__ dinv, int n) {
    int i = blockIdx.x * 256 + threadIdx.x;
    if (i >= n) return;
    int inclusive = inc[i] + blockSums[blockIdx.x];
    int exclusive = inclusive - cnt[i];
    offs[i]   = exclusive;
    cursor[i] = exclusive;
    if ((i & ((1 << BSHIFT) - 1)) == 0) bucketCursor[i >> BSHIFT] = exclusive;
    if (i == n - 1) offs[n] = inclusive;
    dinv[i] = rsqrtf((float)(cnt[i] + 1));  // deg = indeg + 1 (self loop)
}

// Phase 1: bin edges into NBUCK coarse buckets (contiguous node ranges), writing
// (src,dst) pairs in contiguous per-(block,bucket) runs -> write-combine friendly.
constexpr int EPT = 16;  // edges per thread; chunk = 256*EPT = 4096
__global__ __launch_bounds__(256) void partition_edges(
    const int* __restrict__ src, const int* __restrict__ dst,
    int* __restrict__ bucketCursor, int2* __restrict__ pairs, int ne) {
    __shared__ int lcnt[NBUCK];
    __shared__ int lbase[NBUCK];
    int base = blockIdx.x * (256 * EPT);
    if (threadIdx.x < NBUCK) lcnt[threadIdx.x] = 0;
    __syncthreads();
    int2 ed[EPT];
    int  rnk[EPT];
#pragma unroll
    for (int j = 0; j < EPT; ++j) {
        int e = base + j * 256 + threadIdx.x;
        if (e < ne) {
            int d = dst[e];
            ed[j] = make_int2(src[e], d);
            rnk[j] = atomicAdd(&lcnt[d >> BSHIFT], 1);
        } else {
            ed[j].y = -1;
        }
    }
    __syncthreads();
    if (threadIdx.x < NBUCK) {
        int c = lcnt[threadIdx.x];
        lbase[threadIdx.x] = c ? atomicAdd(&bucketCursor[threadIdx.x], c) : 0;
    }
    __syncthreads();
#pragma unroll
    for (int j = 0; j < EPT; ++j) {
        if (ed[j].y >= 0) {
            int b = ed[j].y >> BSHIFT;
            pairs[lbase[b] + rnk[j]] = ed[j];
        }
    }
}

// Phase 2: per-bucket local scatter. The bucket's csr window (~20KB) stays hot
// in the owning XCD's L2, so writebacks ~= useful bytes. 2 blocks per bucket.
__global__ __launch_bounds__(256) void fill_local(
    const int2* __restrict__ pairs, const int* __restrict__ offs,
    int* __restrict__ cursor, int* __restrict__ csr, int n) {
    int b = blockIdx.x >> 1;
    int half = blockIdx.x & 1;
    int nodeLo = b << BSHIFT;
    if (nodeLo >= n) return;
    int nodeHi = nodeLo + (1 << BSHIFT);
    if (nodeHi > n) nodeHi = n;
    int e0 = offs[nodeLo], e1 = offs[nodeHi];
    int mid = e0 + ((e1 - e0) >> 1);
    int s = half ? mid : e0;
    int t = half ? e1 : mid;
    for (int e = s + threadIdx.x; e < t; e += 256) {
        int2 p = pairs[e];
        int pos = atomicAdd(&cursor[p.y], 1);
        csr[pos] = p.x;
    }
}

// ---------------- aggregation (8-way unrolled edge loop) ----------------
template <int M, int TPN, bool SCALE_SRC, bool RELU_BIAS>
__global__ __launch_bounds__(256) void aggregate(
    const float* __restrict__ s, const int* __restrict__ offs,
    const int* __restrict__ csr, const float* __restrict__ dinv,
    const float* __restrict__ b, float* __restrict__ out, int n) {
    int f = threadIdx.x % TPN;
    int node = blockIdx.x * (blockDim.x / TPN) + threadIdx.x / TPN;
    if (node >= n) return;
    bool active = (TPN == M) || (f < M);
    float dv = dinv[node];

    float self_v = active ? s[(long long)node * M + f] : 0.0f;
    float a0 = SCALE_SRC ? self_v * dv : self_v;
    float a1 = 0.0f, a2 = 0.0f, a3 = 0.0f;

    int e0 = offs[node], e1 = offs[node + 1];
    int e = e0;
    for (; e + 8 <= e1; e += 8) {
        int sid[8];
#pragma unroll
        for (int j = 0; j < 8; ++j) sid[j] = csr[e + j];
        float v[8];
#pragma unroll
        for (int j = 0; j < 8; ++j) v[j] = active ? s[(long long)sid[j] * M + f] : 0.0f;
        if (SCALE_SRC) {
#pragma unroll
            for (int j = 0; j < 8; ++j) v[j] *= dinv[sid[j]];
        }
        a0 += v[0] + v[4]; a1 += v[1] + v[5]; a2 += v[2] + v[6]; a3 += v[3] + v[7];
    }
    for (; e + 4 <= e1; e += 4) {
        int s0 = csr[e], s1 = csr[e + 1], s2 = csr[e + 2], s3 = csr[e + 3];
        float v0 = 0.f, v1 = 0.f, v2 = 0.f, v3 = 0.f;
        if (active) {
            v0 = s[(long long)s0 * M + f];
            v1 = s[(long long)s1 * M + f];
            v2 = s[(long long)s2 * M + f];
            v3 = s[(long long)s3 * M + f];
        }
        if (SCALE_SRC) { v0 *= dinv[s0]; v1 *= dinv[s1]; v2 *= dinv[s2]; v3 *= dinv[s3]; }
        a0 += v0; a1 += v1; a2 += v2; a3 += v3;
    }
    for (; e < e1; ++e) {
        int sid = csr[e];
        float v = active ? s[(long long)sid * M + f] : 0.0f;
        if (SCALE_SRC) v *= dinv[sid];
        a0 += v;
    }
    float acc = (a0 + a1) + (a2 + a3);

    if (active) {
        float r = dv * acc;
        if (RELU_BIAS) r = fmaxf(r + b[f], 0.0f);
        out[(long long)node * M + f] = r;
    }
}

// ---------------- register-tiled GEMM (unchanged from R2) ----------------
template <int K, int M, int NT, bool SCALE, bool BIAS_RELU>
__global__ __launch_bounds__(256) void gemm_tiled(
    const float* __restrict__ x, const float* __restrict__ W,
    const float* __restrict__ dinv, const float* __restrict__ b,
    float* __restrict__ out, int n) {
    static_assert(NT % 4 == 0 && K % 2 == 0, "");
    constexpr int Mp  = (M + 3) & ~3;
    constexpr int MQ  = Mp / 4;
    constexpr int NTp = (NT + 4) & ~3;
    constexpr int NTILES = (NT / 4) * MQ;
    static_assert(NTILES <= 256, "");

    __shared__ float Xs[K * NTp];
    __shared__ float Ws[K * Mp];

    for (int i = threadIdx.x; i < K * Mp; i += 256) {
        int k = i / Mp, m = i - k * Mp;
        Ws[i] = (m < M) ? W[k * M + m] : 0.0f;
    }
    int nodeBase = blockIdx.x * NT;
    for (int t = threadIdx.x; t < NT * (K / 2); t += 256) {
        int node = t / (K / 2);
        int k2 = t - node * (K / 2);
        int gn = nodeBase + node;
        float2 v = make_float2(0.0f, 0.0f);
        if (gn < n) v = *(const float2*)&x[(long long)gn * K + k2 * 2];
        Xs[(k2 * 2)     * NTp + node] = v.x;
        Xs[(k2 * 2 + 1) * NTp + node] = v.y;
    }
    __syncthreads();

    int t = threadIdx.x;
    if (t >= NTILES) return;
    int ng = t / MQ, mq = t - ng * MQ;
    int n0 = ng * 4;
    int m0 = mq * 4;

    float acc[4][4];
#pragma unroll
    for (int j = 0; j < 4; ++j)
#pragma unroll
        for (int i = 0; i < 4; ++i) acc[j][i] = 0.0f;

#pragma unroll 2
    for (int k = 0; k < K; ++k) {
        float4 xv = *(const float4*)&Xs[k * NTp + n0];
        float4 wv = *(const float4*)&Ws[k * Mp + m0];
        acc[0][0] = fmaf(xv.x, wv.x, acc[0][0]);
        acc[0][1] = fmaf(xv.x, wv.y, acc[0][1]);
        acc[0][2] = fmaf(xv.x, wv.z, acc[0][2]);
        acc[0][3] = fmaf(xv.x, wv.w, acc[0][3]);
        acc[1][0] = fmaf(xv.y, wv.x, acc[1][0]);
        acc[1][1] = fmaf(xv.y, wv.y, acc[1][1]);
        acc[1][2] = fmaf(xv.y, wv.z, acc[1][2]);
        acc[1][3] = fmaf(xv.y, wv.w, acc[1][3]);
        acc[2][0] = fmaf(xv.z, wv.x, acc[2][0]);
        acc[2][1] = fmaf(xv.z, wv.y, acc[2][1]);
        acc[2][2] = fmaf(xv.z, wv.z, acc[2][2]);
        acc[2][3] = fmaf(xv.z, wv.w, acc[2][3]);
        acc[3][0] = fmaf(xv.w, wv.x, acc[3][0]);
        acc[3][1] = fmaf(xv.w, wv.y, acc[3][1]);
        acc[3][2] = fmaf(xv.w, wv.z, acc[3][2]);
        acc[3][3] = fmaf(xv.w, wv.w, acc[3][3]);
    }

#pragma unroll
    for (int j = 0; j < 4; ++j) {
        int nd = nodeBase + n0 + j;
        if (nd >= n) continue;
        float dv = SCALE ? dinv[nd] : 1.0f;
#pragma unroll
        for (int i = 0; i < 4; ++i) {
            int m = m0 + i;
            if (m < M) {
                float r = acc[j][i];
                if (SCALE) r *= dv;
                if (BIAS_RELU) r = fmaxf(r + b[m], 0.0f);
                out[(long long)nd * M + m] = r;
            }
        }
    }
}

// ---------------- fused 3-layer MLP: 25 -> 25 -> 10 -> 1, relu each ----------------

__global__ void mlp3(const float* __restrict__ x,
                     const float* __restrict__ Wl1, const float* __restrict__ bl1,
                     const float* __restrict__ Wl2, const float* __restrict__ bl2,
                     const float* __restrict__ Wl3, const float* __restrict__ bl3,
                     float* __restrict__ out, int n) {
    __shared__ float W1s[25 * 25], W2s[25 * 10], W3s[10], b1s[25], b2s[10], b3s;
    for (int i = threadIdx.x; i < 625; i += blockDim.x) W1s[i] = Wl1[i];
    for (int i = threadIdx.x; i < 250; i += blockDim.x) W2s[i] = Wl2[i];
    if (threadIdx.x < 10) { W3s[threadIdx.x] = Wl3[threadIdx.x]; b2s[threadIdx.x] = bl2[threadIdx.x]; }
    if (threadIdx.x < 25) b1s[threadIdx.x] = bl1[threadIdx.x];
    if (threadIdx.x == 0) b3s = bl3[0];
    __syncthreads();
    int node = blockIdx.x * blockDim.x + threadIdx.x;
    if (node >= n) return;
    float xr[25];
#pragma unroll
    for (int k = 0; k < 25; ++k) xr[k] = x[(long long)node * 25 + k];
    float h1[25];
#pragma unroll
    for (int m = 0; m < 25; ++m) {
        float a = b1s[m];
#pragma unroll
        for (int k = 0; k < 25; ++k) a = fmaf(xr[k], W1s[k * 25 + m], a);
        h1[m] = fmaxf(a, 0.0f);
    }
    float h2[10];
#pragma unroll
    for (int m = 0; m < 10; ++m) {
        float a = b2s[m];
#pragma unroll
        for (int k = 0; k < 25; ++k) a = fmaf(h1[k], W2s[k * 10 + m], a);
        h2[m] = fmaxf(a, 0.0f);
    }
    float a = b3s;
#pragma unroll
    for (int k = 0; k < 10; ++k) a = fmaf(h2[k], W3s[k], a);
    out[node] = fmaxf(a, 0.0f);
}

// ---------------- launch ----------------

extern "C" void kernel_launch(void* const* d_in, const int* in_sizes, int n_in,
                              void* d_out, int out_size, void* d_ws, size_t ws_size,
                              hipStream_t stream) {
    const float* x0  = (const float*)d_in[0];
    const float* W1  = (const float*)d_in[1];
    const float* b1  = (const float*)d_in[2];
    const float* W2  = (const float*)d_in[3];
    const float* b2  = (const float*)d_in[4];
    const float* W3  = (const float*)d_in[5];
    const float* b3  = (const float*)d_in[6];
    const float* Wl1 = (const float*)d_in[7];
    const float* bl1 = (const float*)d_in[8];
    const float* Wl2 = (const float*)d_in[9];
    const float* bl2 = (const float*)d_in[10];
    const float* Wl3 = (const float*)d_in[11];
    const float* bl3 = (const float*)d_in[12];
    const int*   edge = (const int*)d_in[13];

    int n  = in_sizes[0] / 64;      // 100000
    int ne = in_sizes[13] / 2;      // 1000000
    const int* esrc = edge;
    const int* edst = edge + ne;

    char* ws = (char*)d_ws;
    auto alloc = [&](size_t bytes) {
        char* p = ws;
        ws += (bytes + 255) & ~(size_t)255;
        return p;
    };
    int*   cnt       = (int*)alloc((size_t)n * 4);
    int*   offs      = (int*)alloc((size_t)(n + 1) * 4);
    int*   cursor    = (int*)alloc((size_t)n * 4);
    int*   inc       = (int*)alloc((size_t)n * 4);
    int*   blockSums = (int*)alloc(512 * 4);
    int*   bucketCur = (int*)alloc(NBUCK * 4);
    int*   csr       = (int*)alloc((size_t)ne * 4);
    float* dinv      = (float*)alloc((size_t)n * 4);
    float* bufA      = (float*)alloc((size_t)n * 100 * 4);
    float* bufB      = (float*)alloc((size_t)n * 100 * 4);
    int2*  pairs     = (int2*)bufA;   // alias: consumed before bufA is written
    (void)ws_size; (void)n_in; (void)out_size;

    int nb  = (n + 255) / 256;
    int neb = (ne + 255) / 256;
    int nbuckets = (n + (1 << BSHIFT) - 1) >> BSHIFT;

    // CSR + dinv
    zero_ints<<<nb, 256, 0, stream>>>(cnt, n);
    count_edges<<<neb, 256, 0, stream>>>(edst, cnt, ne);
    scan_blocks<<<nb, 256, 0, stream>>>(cnt, inc, blockSums, n);
    scan_partials<<<1, 512, 0, stream>>>(blockSums, nb);
    finalize_offsets<<<nb, 256, 0, stream>>>(cnt, inc, blockSums, offs, cursor,
                                             bucketCur, dinv, n);
    partition_edges<<<(ne + 256 * EPT - 1) / (256 * EPT), 256, 0, stream>>>(
        esrc, edst, bucketCur, pairs, ne);
    fill_local<<<2 * nbuckets, 256, 0, stream>>>(pairs, offs, cursor, csr, n);

    // Layer 1 (aggregate-first): bufA = ÂX [n,64]; bufB = relu(bufA@W1+b1) [n,100]
    aggregate<64, 64, true, false><<<(n + 3) / 4, 256, 0, stream>>>(
        x0, offs, csr, dinv, nullptr, bufA, n);
    gemm_tiled<64, 100, 40, false, true><<<(n + 39) / 40, 256, 0, stream>>>(
        bufA, W1, nullptr, b1, bufB, n);

    // Layer 2: transform-then-aggregate
    gemm_tiled<100, 50, 76, true, false><<<(n + 75) / 76, 256, 0, stream>>>(
        bufB, W2, dinv, nullptr, bufA, n);
    aggregate<50, 64, false, true><<<(n + 3) / 4, 256, 0, stream>>>(
        bufA, offs, csr, dinv, b2, bufB, n);

    // Layer 3: 50 -> 25
    gemm_tiled<50, 25, 144, true, false><<<(n + 143) / 144, 256, 0, stream>>>(
        bufB, W3, dinv, nullptr, bufA, n);
    aggregate<25, 32, false, true><<<(n + 7) / 8, 256, 0, stream>>>(
        bufA, offs, csr, dinv, b3, bufB, n);

    // fused MLP head
    mlp3<<<nb, 256, 0, stream>>>(bufB, Wl1, bl1, Wl2, bl2, Wl3, bl3, (float*)d_out, n);
}

// Round 5
// 413.028 us; speedup vs baseline: 2.0705x; 1.0720x over previous
//
#include <hip/hip_runtime.h>
#include <cstdint>

constexpr int BSHIFT = 9;               // 512 nodes per bucket
constexpr int NBUCK  = 256;             // covers up to 131072 nodes

__device__ __forceinline__ float4 add4(float4 a, float4 b) {
    return make_float4(a.x + b.x, a.y + b.y, a.z + b.z, a.w + b.w);
}
__device__ __forceinline__ float4 mul4s(float4 a, float s) {
    return make_float4(a.x * s, a.y * s, a.z * s, a.w * s);
}

// ---------------- CSR build ----------------

__global__ void zero_ints(int* __restrict__ p, int n) {
    int i = blockIdx.x * blockDim.x + threadIdx.x;
    if (i < n) p[i] = 0;
}

__global__ void count_edges(const int* __restrict__ dst, int* __restrict__ cnt, int ne) {
    int e = blockIdx.x * blockDim.x + threadIdx.x;
    if (e < ne) atomicAdd(&cnt[dst[e]], 1);
}

__global__ void scan_blocks(const int* __restrict__ cnt, int* __restrict__ inc,
                            int* __restrict__ blockSums, int n) {
    __shared__ int tmp[256];
    int i = blockIdx.x * 256 + threadIdx.x;
    tmp[threadIdx.x] = (i < n) ? cnt[i] : 0;
    __syncthreads();
    for (int off = 1; off < 256; off <<= 1) {
        int t = (threadIdx.x >= (unsigned)off) ? tmp[threadIdx.x - off] : 0;
        __syncthreads();
        tmp[threadIdx.x] += t;
        __syncthreads();
    }
    if (i < n) inc[i] = tmp[threadIdx.x];
    if (threadIdx.x == 255) blockSums[blockIdx.x] = tmp[255];
}

__global__ void scan_partials(int* __restrict__ blockSums, int nb) {
    __shared__ int tmp[512];
    tmp[threadIdx.x] = (threadIdx.x < (unsigned)nb) ? blockSums[threadIdx.x] : 0;
    __syncthreads();
    for (int off = 1; off < 512; off <<= 1) {
        int t = (threadIdx.x >= (unsigned)off) ? tmp[threadIdx.x - off] : 0;
        __syncthreads();
        tmp[threadIdx.x] += t;
        __syncthreads();
    }
    int excl = (threadIdx.x == 0) ? 0 : tmp[threadIdx.x - 1];
    if (threadIdx.x < (unsigned)nb) blockSums[threadIdx.x] = excl;
}

__global__ void finalize_offsets(const int* __restrict__ cnt, const int* __restrict__ inc,
                                 const int* __restrict__ blockSums, int* __restrict__ offs,
                                 int* __restrict__ cursor, int* __restrict__ bucketCursor,
                                 float* __restrict__ dinv, int n) {
    int i = blockIdx.x * 256 + threadIdx.x;
    if (i >= n) return;
    int inclusive = inc[i] + blockSums[blockIdx.x];
    int exclusive = inclusive - cnt[i];
    offs[i]   = exclusive;
    cursor[i] = exclusive;
    if ((i & ((1 << BSHIFT) - 1)) == 0) bucketCursor[i >> BSHIFT] = exclusive;
    if (i == n - 1) offs[n] = inclusive;
    dinv[i] = rsqrtf((float)(cnt[i] + 1));  // deg = indeg + 1 (self loop)
}

constexpr int EPT = 16;  // edges per thread; chunk = 256*EPT = 4096
__global__ __launch_bounds__(256) void partition_edges(
    const int* __restrict__ src, const int* __restrict__ dst,
    int* __restrict__ bucketCursor, int2* __restrict__ pairs, int ne) {
    __shared__ int lcnt[NBUCK];
    __shared__ int lbase[NBUCK];
    int base = blockIdx.x * (256 * EPT);
    if (threadIdx.x < NBUCK) lcnt[threadIdx.x] = 0;
    __syncthreads();
    int2 ed[EPT];
    int  rnk[EPT];
#pragma unroll
    for (int j = 0; j < EPT; ++j) {
        int e = base + j * 256 + threadIdx.x;
        if (e < ne) {
            int d = dst[e];
            ed[j] = make_int2(src[e], d);
            rnk[j] = atomicAdd(&lcnt[d >> BSHIFT], 1);
        } else {
            ed[j].y = -1;
        }
    }
    __syncthreads();
    if (threadIdx.x < NBUCK) {
        int c = lcnt[threadIdx.x];
        lbase[threadIdx.x] = c ? atomicAdd(&bucketCursor[threadIdx.x], c) : 0;
    }
    __syncthreads();
#pragma unroll
    for (int j = 0; j < EPT; ++j) {
        if (ed[j].y >= 0) {
            int b = ed[j].y >> BSHIFT;
            pairs[lbase[b] + rnk[j]] = ed[j];
        }
    }
}

__global__ __launch_bounds__(256) void fill_local(
    const int2* __restrict__ pairs, const int* __restrict__ offs,
    int* __restrict__ cursor, int* __restrict__ csr, int n) {
    int b = blockIdx.x >> 1;
    int half = blockIdx.x & 1;
    int nodeLo = b << BSHIFT;
    if (nodeLo >= n) return;
    int nodeHi = nodeLo + (1 << BSHIFT);
    if (nodeHi > n) nodeHi = n;
    int e0 = offs[nodeLo], e1 = offs[nodeHi];
    int mid = e0 + ((e1 - e0) >> 1);
    int s = half ? mid : e0;
    int t = half ? e1 : mid;
    for (int e = s + threadIdx.x; e < t; e += 256) {
        int2 p = pairs[e];
        int pos = atomicAdd(&cursor[p.y], 1);
        csr[pos] = p.x;
    }
}

// ---------------- aggregation: float4/lane, LPN lanes per node ----------------
// S = feature stride (padded). Each wave hosts 64/LPN independent node chains;
// unroll-4 edge loop -> 4*(64/LPN) outstanding 16B loads per wave.
template <int M, int S, int LPN, bool SCALE_SRC, bool RELU_BIAS>
__global__ __launch_bounds__(256) void aggregate(
    const float* __restrict__ s, const int* __restrict__ offs,
    const int* __restrict__ csr, const float* __restrict__ dinv,
    const float* __restrict__ b, float* __restrict__ out, int n) {
    int lane = threadIdx.x % LPN;
    int node = blockIdx.x * (256 / LPN) + threadIdx.x / LPN;
    if (node >= n) return;
    int f0 = lane * 4;
    bool active = f0 < M;
    float dv = dinv[node];

    float4 z = make_float4(0.f, 0.f, 0.f, 0.f);
    float4 acc0 = z, acc1 = z, acc2 = z, acc3 = z;
    if (active) {
        float4 sv = *(const float4*)&s[(size_t)node * S + f0];
        acc0 = SCALE_SRC ? mul4s(sv, dv) : sv;
    }

    int e0 = offs[node], e1 = offs[node + 1];
    int e = e0;
    for (; e + 4 <= e1; e += 4) {
        int i0 = csr[e], i1 = csr[e + 1], i2 = csr[e + 2], i3 = csr[e + 3];
        float4 v0 = z, v1 = z, v2 = z, v3 = z;
        if (active) {
            v0 = *(const float4*)&s[(size_t)i0 * S + f0];
            v1 = *(const float4*)&s[(size_t)i1 * S + f0];
            v2 = *(const float4*)&s[(size_t)i2 * S + f0];
            v3 = *(const float4*)&s[(size_t)i3 * S + f0];
        }
        if (SCALE_SRC) {
            v0 = mul4s(v0, dinv[i0]); v1 = mul4s(v1, dinv[i1]);
            v2 = mul4s(v2, dinv[i2]); v3 = mul4s(v3, dinv[i3]);
        }
        acc0 = add4(acc0, v0); acc1 = add4(acc1, v1);
        acc2 = add4(acc2, v2); acc3 = add4(acc3, v3);
    }
    for (; e < e1; ++e) {
        int sid = csr[e];
        float4 v = active ? *(const float4*)&s[(size_t)sid * S + f0] : z;
        if (SCALE_SRC) v = mul4s(v, dinv[sid]);
        acc0 = add4(acc0, v);
    }
    float4 acc = add4(add4(acc0, acc1), add4(acc2, acc3));

    if (active) {
        float4 r = mul4s(acc, dv);
        if (RELU_BIAS) {
            if (f0 + 0 < M) r.x = fmaxf(r.x + b[f0 + 0], 0.0f);
            if (f0 + 1 < M) r.y = fmaxf(r.y + b[f0 + 1], 0.0f);
            if (f0 + 2 < M) r.z = fmaxf(r.z + b[f0 + 2], 0.0f);
            if (f0 + 3 < M) r.w = fmaxf(r.w + b[f0 + 3], 0.0f);
        }
        float* o = &out[(size_t)node * S + f0];
        if (f0 + 3 < M) {
            *(float4*)o = r;
        } else {
            if (f0 + 0 < M) o[0] = r.x;
            if (f0 + 1 < M) o[1] = r.y;
            if (f0 + 2 < M) o[2] = r.z;
            if (f0 + 3 < M) o[3] = r.w;
        }
    }
}

// ---------------- register-tiled GEMM, conflict-free staging ----------------
// XS / OS = input / output feature strides. NTp chosen ==4 (mod 8) so the
// transpose-staging LDS writes (stride 4*NTp words) land 16 banks apart
// (2-way = free); compute reads are <=2-way as before.
template <int K, int M, int NT, int XS, int OS, bool SCALE, bool BIAS_RELU>
__global__ __launch_bounds__(256) void gemm_tiled(
    const float* __restrict__ x, const float* __restrict__ W,
    const float* __restrict__ dinv, const float* __restrict__ b,
    float* __restrict__ out, int n) {
    static_assert(NT % 4 == 0 && K % 2 == 0, "");
    constexpr int Mp  = (M + 3) & ~3;
    constexpr int MQ  = Mp / 4;
    constexpr int NTp0 = NT + 4;
    constexpr int NTp  = (NTp0 % 8 == 0) ? NTp0 + 4 : NTp0;   // ==4 mod 8
    constexpr int NTILES = (NT / 4) * MQ;
    static_assert(NTILES <= 256, "");

    __shared__ float Xs[K * NTp];
    __shared__ float Ws[K * Mp];

    for (int i = threadIdx.x; i < K * Mp; i += 256) {
        int k = i / Mp, m = i - k * Mp;
        Ws[i] = (m < M) ? W[k * M + m] : 0.0f;
    }
    int nodeBase = blockIdx.x * NT;
    if (K % 4 == 0) {
        for (int t = threadIdx.x; t < NT * (K / 4); t += 256) {
            int node = t / (K / 4);
            int kq = t - node * (K / 4);
            int gn = nodeBase + node;
            float4 v = make_float4(0.f, 0.f, 0.f, 0.f);
            if (gn < n) v = *(const float4*)&x[(size_t)gn * XS + kq * 4];
            Xs[(kq * 4 + 0) * NTp + node] = v.x;
            Xs[(kq * 4 + 1) * NTp + node] = v.y;
            Xs[(kq * 4 + 2) * NTp + node] = v.z;
            Xs[(kq * 4 + 3) * NTp + node] = v.w;
        }
    } else {
        for (int t = threadIdx.x; t < NT * (K / 2); t += 256) {
            int node = t / (K / 2);
            int k2 = t - node * (K / 2);
            int gn = nodeBase + node;
            float2 v = make_float2(0.f, 0.f);
            if (gn < n) v = *(const float2*)&x[(size_t)gn * XS + k2 * 2];
            Xs[(k2 * 2 + 0) * NTp + node] = v.x;
            Xs[(k2 * 2 + 1) * NTp + node] = v.y;
        }
    }
    __syncthreads();

    int t = threadIdx.x;
    if (t >= NTILES) return;
    int ng = t / MQ, mq = t - ng * MQ;
    int n0 = ng * 4;
    int m0 = mq * 4;

    float acc[4][4];
#pragma unroll
    for (int j = 0; j < 4; ++j)
#pragma unroll
        for (int i = 0; i < 4; ++i) acc[j][i] = 0.0f;

#pragma unroll 2
    for (int k = 0; k < K; ++k) {
        float4 xv = *(const float4*)&Xs[k * NTp + n0];
        float4 wv = *(const float4*)&Ws[k * Mp + m0];
        acc[0][0] = fmaf(xv.x, wv.x, acc[0][0]);
        acc[0][1] = fmaf(xv.x, wv.y, acc[0][1]);
        acc[0][2] = fmaf(xv.x, wv.z, acc[0][2]);
        acc[0][3] = fmaf(xv.x, wv.w, acc[0][3]);
        acc[1][0] = fmaf(xv.y, wv.x, acc[1][0]);
        acc[1][1] = fmaf(xv.y, wv.y, acc[1][1]);
        acc[1][2] = fmaf(xv.y, wv.z, acc[1][2]);
        acc[1][3] = fmaf(xv.y, wv.w, acc[1][3]);
        acc[2][0] = fmaf(xv.z, wv.x, acc[2][0]);
        acc[2][1] = fmaf(xv.z, wv.y, acc[2][1]);
        acc[2][2] = fmaf(xv.z, wv.z, acc[2][2]);
        acc[2][3] = fmaf(xv.z, wv.w, acc[2][3]);
        acc[3][0] = fmaf(xv.w, wv.x, acc[3][0]);
        acc[3][1] = fmaf(xv.w, wv.y, acc[3][1]);
        acc[3][2] = fmaf(xv.w, wv.z, acc[3][2]);
        acc[3][3] = fmaf(xv.w, wv.w, acc[3][3]);
    }

#pragma unroll
    for (int j = 0; j < 4; ++j) {
        int nd = nodeBase + n0 + j;
        if (nd >= n) continue;
        float dv = SCALE ? dinv[nd] : 1.0f;
#pragma unroll
        for (int i = 0; i < 4; ++i) {
            int m = m0 + i;
            if (m < M) {
                float r = acc[j][i];
                if (SCALE) r *= dv;
                if (BIAS_RELU) r = fmaxf(r + b[m], 0.0f);
                out[(size_t)nd * OS + m] = r;
            }
        }
    }
}

// ---------------- fused 3-layer MLP: 25 -> 25 -> 10 -> 1 (input stride 32) ----------------

__global__ void mlp3(const float* __restrict__ x,
                     const float* __restrict__ Wl1, const float* __restrict__ bl1,
                     const float* __restrict__ Wl2, const float* __restrict__ bl2,
                     const float* __restrict__ Wl3, const float* __restrict__ bl3,
                     float* __restrict__ out, int n) {
    __shared__ float W1s[25 * 25], W2s[25 * 10], W3s[10], b1s[25], b2s[10], b3s;
    for (int i = threadIdx.x; i < 625; i += blockDim.x) W1s[i] = Wl1[i];
    for (int i = threadIdx.x; i < 250; i += blockDim.x) W2s[i] = Wl2[i];
    if (threadIdx.x < 10) { W3s[threadIdx.x] = Wl3[threadIdx.x]; b2s[threadIdx.x] = bl2[threadIdx.x]; }
    if (threadIdx.x < 25) b1s[threadIdx.x] = bl1[threadIdx.x];
    if (threadIdx.x == 0) b3s = bl3[0];
    __syncthreads();
    int node = blockIdx.x * blockDim.x + threadIdx.x;
    if (node >= n) return;
    float xr[25];
#pragma unroll
    for (int k = 0; k < 25; ++k) xr[k] = x[(size_t)node * 32 + k];
    float h1[25];
#pragma unroll
    for (int m = 0; m < 25; ++m) {
        float a = b1s[m];
#pragma unroll
        for (int k = 0; k < 25; ++k) a = fmaf(xr[k], W1s[k * 25 + m], a);
        h1[m] = fmaxf(a, 0.0f);
    }
    float h2[10];
#pragma unroll
    for (int m = 0; m < 10; ++m) {
        float a = b2s[m];
#pragma unroll
        for (int k = 0; k < 25; ++k) a = fmaf(h1[k], W2s[k * 10 + m], a);
        h2[m] = fmaxf(a, 0.0f);
    }
    float a = b3s;
#pragma unroll
    for (int k = 0; k < 10; ++k) a = fmaf(h2[k], W3s[k], a);
    out[node] = fmaxf(a, 0.0f);
}

// ---------------- launch ----------------

extern "C" void kernel_launch(void* const* d_in, const int* in_sizes, int n_in,
                              void* d_out, int out_size, void* d_ws, size_t ws_size,
                              hipStream_t stream) {
    const float* x0  = (const float*)d_in[0];
    const float* W1  = (const float*)d_in[1];
    const float* b1  = (const float*)d_in[2];
    const float* W2  = (const float*)d_in[3];
    const float* b2  = (const float*)d_in[4];
    const float* W3  = (const float*)d_in[5];
    const float* b3  = (const float*)d_in[6];
    const float* Wl1 = (const float*)d_in[7];
    const float* bl1 = (const float*)d_in[8];
    const float* Wl2 = (const float*)d_in[9];
    const float* bl2 = (const float*)d_in[10];
    const float* Wl3 = (const float*)d_in[11];
    const float* bl3 = (const float*)d_in[12];
    const int*   edge = (const int*)d_in[13];

    int n  = in_sizes[0] / 64;      // 100000
    int ne = in_sizes[13] / 2;      // 1000000
    const int* esrc = edge;
    const int* edst = edge + ne;

    char* ws = (char*)d_ws;
    auto alloc = [&](size_t bytes) {
        char* p = ws;
        ws += (bytes + 255) & ~(size_t)255;
        return p;
    };
    int*   cnt       = (int*)alloc((size_t)n * 4);
    int*   offs      = (int*)alloc((size_t)(n + 1) * 4);
    int*   cursor    = (int*)alloc((size_t)n * 4);
    int*   inc       = (int*)alloc((size_t)n * 4);
    int*   blockSums = (int*)alloc(512 * 4);
    int*   bucketCur = (int*)alloc(NBUCK * 4);
    int*   csr       = (int*)alloc((size_t)ne * 4);
    float* dinv      = (float*)alloc((size_t)n * 4);
    float* bufA      = (float*)alloc((size_t)n * 64 * 4);   // stride-64 buffer
    float* bufB      = (float*)alloc((size_t)n * 100 * 4);  // stride-100 / reused stride-64/32
    int2*  pairs     = (int2*)bufA;   // alias: consumed (fill_local) before bufA written
    (void)ws_size; (void)n_in; (void)out_size;

    int nb  = (n + 255) / 256;
    int neb = (ne + 255) / 256;
    int nbuckets = (n + (1 << BSHIFT) - 1) >> BSHIFT;

    // CSR + dinv
    zero_ints<<<nb, 256, 0, stream>>>(cnt, n);
    count_edges<<<neb, 256, 0, stream>>>(edst, cnt, ne);
    scan_blocks<<<nb, 256, 0, stream>>>(cnt, inc, blockSums, n);
    scan_partials<<<1, 512, 0, stream>>>(blockSums, nb);
    finalize_offsets<<<nb, 256, 0, stream>>>(cnt, inc, blockSums, offs, cursor,
                                             bucketCur, dinv, n);
    partition_edges<<<(ne + 256 * EPT - 1) / (256 * EPT), 256, 0, stream>>>(
        esrc, edst, bucketCur, pairs, ne);
    fill_local<<<2 * nbuckets, 256, 0, stream>>>(pairs, offs, cursor, csr, n);

    // Layer 1 (aggregate-first): bufA = ÂX (stride 64); bufB = relu(bufA@W1+b1) (stride 100)
    aggregate<64, 64, 16, true, false><<<(n + 15) / 16, 256, 0, stream>>>(
        x0, offs, csr, dinv, nullptr, bufA, n);
    gemm_tiled<64, 100, 40, 64, 100, false, true><<<(n + 39) / 40, 256, 0, stream>>>(
        bufA, W1, nullptr, b1, bufB, n);

    // Layer 2: bufA = (bufB@W2)*dinv (stride 64); bufB = relu(dinv*agg(bufA)+b2) (stride 64)
    gemm_tiled<100, 50, 64, 100, 64, true, false><<<(n + 63) / 64, 256, 0, stream>>>(
        bufB, W2, dinv, nullptr, bufA, n);
    aggregate<50, 64, 16, false, true><<<(n + 15) / 16, 256, 0, stream>>>(
        bufA, offs, csr, dinv, b2, bufB, n);

    // Layer 3: bufA = (bufB@W3)*dinv (stride 32); bufB = relu(dinv*agg(bufA)+b3) (stride 32)
    gemm_tiled<50, 25, 144, 64, 32, true, false><<<(n + 143) / 144, 256, 0, stream>>>(
        bufB, W3, dinv, nullptr, bufA, n);
    aggregate<25, 32, 8, false, true><<<(n + 31) / 32, 256, 0, stream>>>(
        bufA, offs, csr, dinv, b3, bufB, n);

    // fused MLP head (input stride 32)
    mlp3<<<nb, 256, 0, stream>>>(bufB, Wl1, bl1, Wl2, bl2, Wl3, bl3, (float*)d_out, n);
}

// Round 6
// 393.581 us; speedup vs baseline: 2.1728x; 1.0494x over previous
//
#include <hip/hip_runtime.h>
#include <cstdint>

constexpr int BSHIFT = 9;               // 512 nodes per bucket
constexpr int NBUCK  = 256;             // covers up to 131072 nodes

__device__ __forceinline__ float4 add4(float4 a, float4 b) {
    return make_float4(a.x + b.x, a.y + b.y, a.z + b.z, a.w + b.w);
}
__device__ __forceinline__ float4 mul4s(float4 a, float s) {
    return make_float4(a.x * s, a.y * s, a.z * s, a.w * s);
}

// ---------------- CSR build ----------------

__global__ void zero_ints(int* __restrict__ p, int n) {
    int i = blockIdx.x * blockDim.x + threadIdx.x;
    if (i < n) p[i] = 0;
}

__global__ void count_edges(const int* __restrict__ dst, int* __restrict__ cnt, int ne) {
    int e = blockIdx.x * blockDim.x + threadIdx.x;
    if (e < ne) atomicAdd(&cnt[dst[e]], 1);
}

__global__ void scan_blocks(const int* __restrict__ cnt, int* __restrict__ inc,
                            int* __restrict__ blockSums, int n) {
    __shared__ int tmp[256];
    int i = blockIdx.x * 256 + threadIdx.x;
    tmp[threadIdx.x] = (i < n) ? cnt[i] : 0;
    __syncthreads();
    for (int off = 1; off < 256; off <<= 1) {
        int t = (threadIdx.x >= (unsigned)off) ? tmp[threadIdx.x - off] : 0;
        __syncthreads();
        tmp[threadIdx.x] += t;
        __syncthreads();
    }
    if (i < n) inc[i] = tmp[threadIdx.x];
    if (threadIdx.x == 255) blockSums[blockIdx.x] = tmp[255];
}

__global__ void scan_partials(int* __restrict__ blockSums, int nb) {
    __shared__ int tmp[512];
    tmp[threadIdx.x] = (threadIdx.x < (unsigned)nb) ? blockSums[threadIdx.x] : 0;
    __syncthreads();
    for (int off = 1; off < 512; off <<= 1) {
        int t = (threadIdx.x >= (unsigned)off) ? tmp[threadIdx.x - off] : 0;
        __syncthreads();
        tmp[threadIdx.x] += t;
        __syncthreads();
    }
    int excl = (threadIdx.x == 0) ? 0 : tmp[threadIdx.x - 1];
    if (threadIdx.x < (unsigned)nb) blockSums[threadIdx.x] = excl;
}

__global__ void finalize_offsets(const int* __restrict__ cnt, const int* __restrict__ inc,
                                 const int* __restrict__ blockSums, int* __restrict__ offs,
                                 int* __restrict__ cursor, int* __restrict__ bucketCursor,
                                 float* __restrict__ dinv, int n) {
    int i = blockIdx.x * 256 + threadIdx.x;
    if (i >= n) return;
    int inclusive = inc[i] + blockSums[blockIdx.x];
    int exclusive = inclusive - cnt[i];
    offs[i]   = exclusive;
    cursor[i] = exclusive;
    if ((i & ((1 << BSHIFT) - 1)) == 0) bucketCursor[i >> BSHIFT] = exclusive;
    if (i == n - 1) offs[n] = inclusive;
    dinv[i] = rsqrtf((float)(cnt[i] + 1));  // deg = indeg + 1 (self loop)
}

constexpr int EPT = 16;  // edges per thread; chunk = 256*EPT = 4096
__global__ __launch_bounds__(256) void partition_edges(
    const int* __restrict__ src, const int* __restrict__ dst,
    int* __restrict__ bucketCursor, int2* __restrict__ pairs, int ne) {
    __shared__ int lcnt[NBUCK];
    __shared__ int lbase[NBUCK];
    int base = blockIdx.x * (256 * EPT);
    if (threadIdx.x < NBUCK) lcnt[threadIdx.x] = 0;
    __syncthreads();
    int2 ed[EPT];
    int  rnk[EPT];
#pragma unroll
    for (int j = 0; j < EPT; ++j) {
        int e = base + j * 256 + threadIdx.x;
        if (e < ne) {
            int d = dst[e];
            ed[j] = make_int2(src[e], d);
            rnk[j] = atomicAdd(&lcnt[d >> BSHIFT], 1);
        } else {
            ed[j].y = -1;
        }
    }
    __syncthreads();
    if (threadIdx.x < NBUCK) {
        int c = lcnt[threadIdx.x];
        lbase[threadIdx.x] = c ? atomicAdd(&bucketCursor[threadIdx.x], c) : 0;
    }
    __syncthreads();
#pragma unroll
    for (int j = 0; j < EPT; ++j) {
        if (ed[j].y >= 0) {
            int b = ed[j].y >> BSHIFT;
            pairs[lbase[b] + rnk[j]] = ed[j];
        }
    }
}

__global__ __launch_bounds__(256) void fill_local(
    const int2* __restrict__ pairs, const int* __restrict__ offs,
    int* __restrict__ cursor, int* __restrict__ csr, int n) {
    int b = blockIdx.x >> 1;
    int half = blockIdx.x & 1;
    int nodeLo = b << BSHIFT;
    if (nodeLo >= n) return;
    int nodeHi = nodeLo + (1 << BSHIFT);
    if (nodeHi > n) nodeHi = n;
    int e0 = offs[nodeLo], e1 = offs[nodeHi];
    int mid = e0 + ((e1 - e0) >> 1);
    int s = half ? mid : e0;
    int t = half ? e1 : mid;
    for (int e = s + threadIdx.x; e < t; e += 256) {
        int2 p = pairs[e];
        int pos = atomicAdd(&cursor[p.y], 1);
        csr[pos] = p.x;
    }
}

// ---------------- aggregation: float4/lane, LPN lanes per node ----------------
template <int M, int S, int LPN, bool SCALE_SRC, bool RELU_BIAS>
__global__ __launch_bounds__(256) void aggregate(
    const float* __restrict__ s, const int* __restrict__ offs,
    const int* __restrict__ csr, const float* __restrict__ dinv,
    const float* __restrict__ b, float* __restrict__ out, int n) {
    int lane = threadIdx.x % LPN;
    int node = blockIdx.x * (256 / LPN) + threadIdx.x / LPN;
    if (node >= n) return;
    int f0 = lane * 4;
    bool active = f0 < M;
    float dv = dinv[node];

    float4 z = make_float4(0.f, 0.f, 0.f, 0.f);
    float4 acc0 = z, acc1 = z, acc2 = z, acc3 = z;
    if (active) {
        float4 sv = *(const float4*)&s[(size_t)node * S + f0];
        acc0 = SCALE_SRC ? mul4s(sv, dv) : sv;
    }

    int e0 = offs[node], e1 = offs[node + 1];
    int e = e0;
    for (; e + 4 <= e1; e += 4) {
        int i0 = csr[e], i1 = csr[e + 1], i2 = csr[e + 2], i3 = csr[e + 3];
        float4 v0 = z, v1 = z, v2 = z, v3 = z;
        if (active) {
            v0 = *(const float4*)&s[(size_t)i0 * S + f0];
            v1 = *(const float4*)&s[(size_t)i1 * S + f0];
            v2 = *(const float4*)&s[(size_t)i2 * S + f0];
            v3 = *(const float4*)&s[(size_t)i3 * S + f0];
        }
        if (SCALE_SRC) {
            v0 = mul4s(v0, dinv[i0]); v1 = mul4s(v1, dinv[i1]);
            v2 = mul4s(v2, dinv[i2]); v3 = mul4s(v3, dinv[i3]);
        }
        acc0 = add4(acc0, v0); acc1 = add4(acc1, v1);
        acc2 = add4(acc2, v2); acc3 = add4(acc3, v3);
    }
    for (; e < e1; ++e) {
        int sid = csr[e];
        float4 v = active ? *(const float4*)&s[(size_t)sid * S + f0] : z;
        if (SCALE_SRC) v = mul4s(v, dinv[sid]);
        acc0 = add4(acc0, v);
    }
    float4 acc = add4(add4(acc0, acc1), add4(acc2, acc3));

    if (active) {
        float4 r = mul4s(acc, dv);
        if (RELU_BIAS) {
            if (f0 + 0 < M) r.x = fmaxf(r.x + b[f0 + 0], 0.0f);
            if (f0 + 1 < M) r.y = fmaxf(r.y + b[f0 + 1], 0.0f);
            if (f0 + 2 < M) r.z = fmaxf(r.z + b[f0 + 2], 0.0f);
            if (f0 + 3 < M) r.w = fmaxf(r.w + b[f0 + 3], 0.0f);
        }
        float* o = &out[(size_t)node * S + f0];
        if (f0 + 3 < M) {
            *(float4*)o = r;
        } else {
            if (f0 + 0 < M) o[0] = r.x;
            if (f0 + 1 < M) o[1] = r.y;
            if (f0 + 2 < M) o[2] = r.z;
            if (f0 + 3 < M) o[3] = r.w;
        }
    }
}

// ---------------- register-tiled GEMM, conflict-free node-fast staging ----------------
// X staging enumerates node-fast: each LDS store instr has lanes at consecutive
// `node` addresses -> consecutive banks -> <=2-way (free). Global read is then
// 16B/lane at row stride XS*4 B; XS is a multiple of 16 so rows are whole,
// aligned cache lines (L1/L2 absorbs the per-wave partial-line reads).
// W staged with vectorized linear copies (no per-element div).
template <int K, int M, int NT, int XS, int OS, bool SCALE, bool BIAS_RELU>
__global__ __launch_bounds__(256) void gemm_tiled(
    const float* __restrict__ x, const float* __restrict__ W,
    const float* __restrict__ dinv, const float* __restrict__ b,
    float* __restrict__ out, int n) {
    static_assert(NT % 4 == 0 && K % 2 == 0 && XS % 16 == 0 && OS % 4 == 0, "");
    constexpr int Mp  = (M + 3) & ~3;
    constexpr int MQ  = Mp / 4;
    constexpr int NTp = NT + 4;
    constexpr int NTILES = (NT / 4) * MQ;
    static_assert(NTILES <= 256, "");

    __shared__ float Xs[K * NTp];
    __shared__ float Ws[K * Mp];

    // ---- stage W (vectorized, linear) ----
    if constexpr (M % 4 == 0) {
        for (int i = threadIdx.x; i < K * M / 4; i += 256)
            ((float4*)Ws)[i] = ((const float4*)W)[i];
    } else if constexpr (M % 2 == 0) {
        constexpr int C2 = Mp / 2;
        for (int i = threadIdx.x; i < K * C2; i += 256) {
            int r = i / C2, c = i - r * C2;
            float2 v;
            if (c * 2 + 1 < M)      v = *(const float2*)&W[r * M + c * 2];
            else if (c * 2 < M)     v = make_float2(W[r * M + c * 2], 0.0f);
            else                    v = make_float2(0.0f, 0.0f);
            *(float2*)&Ws[r * Mp + c * 2] = v;
        }
    } else {
        for (int i = threadIdx.x; i < K * Mp; i += 256) {
            int r = i / Mp, c = i - r * Mp;
            Ws[i] = (c < M) ? W[r * M + c] : 0.0f;
        }
    }

    // ---- stage X transposed, node-fast ----
    int nodeBase = blockIdx.x * NT;
    constexpr int KV = (K % 4 == 0) ? 4 : 2;
    for (int it = threadIdx.x; it < NT * (K / KV); it += 256) {
        int node = it % NT;
        int kv = it / NT;
        int gn = nodeBase + node;
        if constexpr (KV == 4) {
            float4 v = make_float4(0.f, 0.f, 0.f, 0.f);
            if (gn < n) v = *(const float4*)&x[(size_t)gn * XS + kv * 4];
            Xs[(kv * 4 + 0) * NTp + node] = v.x;
            Xs[(kv * 4 + 1) * NTp + node] = v.y;
            Xs[(kv * 4 + 2) * NTp + node] = v.z;
            Xs[(kv * 4 + 3) * NTp + node] = v.w;
        } else {
            float2 v = make_float2(0.f, 0.f);
            if (gn < n) v = *(const float2*)&x[(size_t)gn * XS + kv * 2];
            Xs[(kv * 2 + 0) * NTp + node] = v.x;
            Xs[(kv * 2 + 1) * NTp + node] = v.y;
        }
    }
    __syncthreads();

    int t = threadIdx.x;
    if (t >= NTILES) return;
    int ng = t / MQ, mq = t - ng * MQ;
    int n0 = ng * 4;
    int m0 = mq * 4;

    float acc[4][4];
#pragma unroll
    for (int j = 0; j < 4; ++j)
#pragma unroll
        for (int i = 0; i < 4; ++i) acc[j][i] = 0.0f;

#pragma unroll 4
    for (int k = 0; k < K; ++k) {
        float4 xv = *(const float4*)&Xs[k * NTp + n0];
        float4 wv = *(const float4*)&Ws[k * Mp + m0];
        acc[0][0] = fmaf(xv.x, wv.x, acc[0][0]);
        acc[0][1] = fmaf(xv.x, wv.y, acc[0][1]);
        acc[0][2] = fmaf(xv.x, wv.z, acc[0][2]);
        acc[0][3] = fmaf(xv.x, wv.w, acc[0][3]);
        acc[1][0] = fmaf(xv.y, wv.x, acc[1][0]);
        acc[1][1] = fmaf(xv.y, wv.y, acc[1][1]);
        acc[1][2] = fmaf(xv.y, wv.z, acc[1][2]);
        acc[1][3] = fmaf(xv.y, wv.w, acc[1][3]);
        acc[2][0] = fmaf(xv.z, wv.x, acc[2][0]);
        acc[2][1] = fmaf(xv.z, wv.y, acc[2][1]);
        acc[2][2] = fmaf(xv.z, wv.z, acc[2][2]);
        acc[2][3] = fmaf(xv.z, wv.w, acc[2][3]);
        acc[3][0] = fmaf(xv.w, wv.x, acc[3][0]);
        acc[3][1] = fmaf(xv.w, wv.y, acc[3][1]);
        acc[3][2] = fmaf(xv.w, wv.z, acc[3][2]);
        acc[3][3] = fmaf(xv.w, wv.w, acc[3][3]);
    }

#pragma unroll
    for (int j = 0; j < 4; ++j) {
        int nd = nodeBase + n0 + j;
        if (nd >= n) continue;
        float dv = SCALE ? dinv[nd] : 1.0f;
        if (m0 + 3 < M) {
            float4 r = make_float4(acc[j][0], acc[j][1], acc[j][2], acc[j][3]);
            if (SCALE) r = mul4s(r, dv);
            if (BIAS_RELU) {
                r.x = fmaxf(r.x + b[m0 + 0], 0.0f);
                r.y = fmaxf(r.y + b[m0 + 1], 0.0f);
                r.z = fmaxf(r.z + b[m0 + 2], 0.0f);
                r.w = fmaxf(r.w + b[m0 + 3], 0.0f);
            }
            *(float4*)&out[(size_t)nd * OS + m0] = r;
        } else {
#pragma unroll
            for (int i = 0; i < 4; ++i) {
                int m = m0 + i;
                if (m < M) {
                    float r = acc[j][i];
                    if (SCALE) r *= dv;
                    if (BIAS_RELU) r = fmaxf(r + b[m], 0.0f);
                    out[(size_t)nd * OS + m] = r;
                }
            }
        }
    }
}

// ---------------- fused 3-layer MLP: 25 -> 25 -> 10 -> 1 (input stride 32) ----------------

__global__ void mlp3(const float* __restrict__ x,
                     const float* __restrict__ Wl1, const float* __restrict__ bl1,
                     const float* __restrict__ Wl2, const float* __restrict__ bl2,
                     const float* __restrict__ Wl3, const float* __restrict__ bl3,
                     float* __restrict__ out, int n) {
    __shared__ float W1s[25 * 25], W2s[25 * 10], W3s[10], b1s[25], b2s[10], b3s;
    for (int i = threadIdx.x; i < 625; i += blockDim.x) W1s[i] = Wl1[i];
    for (int i = threadIdx.x; i < 250; i += blockDim.x) W2s[i] = Wl2[i];
    if (threadIdx.x < 10) { W3s[threadIdx.x] = Wl3[threadIdx.x]; b2s[threadIdx.x] = bl2[threadIdx.x]; }
    if (threadIdx.x < 25) b1s[threadIdx.x] = bl1[threadIdx.x];
    if (threadIdx.x == 0) b3s = bl3[0];
    __syncthreads();
    int node = blockIdx.x * blockDim.x + threadIdx.x;
    if (node >= n) return;
    float xr[25];
#pragma unroll
    for (int k = 0; k < 25; ++k) xr[k] = x[(size_t)node * 32 + k];
    float h1[25];
#pragma unroll
    for (int m = 0; m < 25; ++m) {
        float a = b1s[m];
#pragma unroll
        for (int k = 0; k < 25; ++k) a = fmaf(xr[k], W1s[k * 25 + m], a);
        h1[m] = fmaxf(a, 0.0f);
    }
    float h2[10];
#pragma unroll
    for (int m = 0; m < 10; ++m) {
        float a = b2s[m];
#pragma unroll
        for (int k = 0; k < 25; ++k) a = fmaf(h1[k], W2s[k * 10 + m], a);
        h2[m] = fmaxf(a, 0.0f);
    }
    float a = b3s;
#pragma unroll
    for (int k = 0; k < 10; ++k) a = fmaf(h2[k], W3s[k], a);
    out[node] = fmaxf(a, 0.0f);
}

// ---------------- launch ----------------

extern "C" void kernel_launch(void* const* d_in, const int* in_sizes, int n_in,
                              void* d_out, int out_size, void* d_ws, size_t ws_size,
                              hipStream_t stream) {
    const float* x0  = (const float*)d_in[0];
    const float* W1  = (const float*)d_in[1];
    const float* b1  = (const float*)d_in[2];
    const float* W2  = (const float*)d_in[3];
    const float* b2  = (const float*)d_in[4];
    const float* W3  = (const float*)d_in[5];
    const float* b3  = (const float*)d_in[6];
    const float* Wl1 = (const float*)d_in[7];
    const float* bl1 = (const float*)d_in[8];
    const float* Wl2 = (const float*)d_in[9];
    const float* bl2 = (const float*)d_in[10];
    const float* Wl3 = (const float*)d_in[11];
    const float* bl3 = (const float*)d_in[12];
    const int*   edge = (const int*)d_in[13];

    int n  = in_sizes[0] / 64;      // 100000
    int ne = in_sizes[13] / 2;      // 1000000
    const int* esrc = edge;
    const int* edst = edge + ne;

    char* ws = (char*)d_ws;
    auto alloc = [&](size_t bytes) {
        char* p = ws;
        ws += (bytes + 255) & ~(size_t)255;
        return p;
    };
    int*   offs      = (int*)alloc((size_t)(n + 1) * 4);
    int*   blockSums = (int*)alloc(512 * 4);
    int*   bucketCur = (int*)alloc(NBUCK * 4);
    int*   csr       = (int*)alloc((size_t)ne * 4);
    float* dinv      = (float*)alloc((size_t)n * 4);
    float* bufA      = (float*)alloc((size_t)n * 64 * 4);    // stride-64 buffer
    float* bufB      = (float*)alloc((size_t)n * 112 * 4);   // stride-112 (64B-aligned rows)
    // transient aliases (dead before their hosts are first written):
    int2*  pairs  = (int2*)bufA;            // consumed by fill_local, before aggregate1 writes bufA
    int*   cnt    = (int*)bufB;             // CSR transients live in bufB until gemm1 writes it
    int*   inc    = (int*)(bufB + (size_t)n);
    int*   cursor = (int*)(bufB + (size_t)2 * n);
    (void)ws_size; (void)n_in; (void)out_size;

    int nb  = (n + 255) / 256;
    int neb = (ne + 255) / 256;
    int nbuckets = (n + (1 << BSHIFT) - 1) >> BSHIFT;

    // CSR + dinv
    zero_ints<<<nb, 256, 0, stream>>>(cnt, n);
    count_edges<<<neb, 256, 0, stream>>>(edst, cnt, ne);
    scan_blocks<<<nb, 256, 0, stream>>>(cnt, inc, blockSums, n);
    scan_partials<<<1, 512, 0, stream>>>(blockSums, nb);
    finalize_offsets<<<nb, 256, 0, stream>>>(cnt, inc, blockSums, offs, cursor,
                                             bucketCur, dinv, n);
    partition_edges<<<(ne + 256 * EPT - 1) / (256 * EPT), 256, 0, stream>>>(
        esrc, edst, bucketCur, pairs, ne);
    fill_local<<<2 * nbuckets, 256, 0, stream>>>(pairs, offs, cursor, csr, n);

    // Layer 1 (aggregate-first): bufA = ÂX (stride 64); bufB = relu(bufA@W1+b1) (stride 112)
    aggregate<64, 64, 16, true, false><<<(n + 15) / 16, 256, 0, stream>>>(
        x0, offs, csr, dinv, nullptr, bufA, n);
    gemm_tiled<64, 100, 40, 64, 112, false, true><<<(n + 39) / 40, 256, 0, stream>>>(
        bufA, W1, nullptr, b1, bufB, n);

    // Layer 2: bufA = (bufB@W2)*dinv (stride 64); bufB = relu(dinv*agg(bufA)+b2) (stride 64)
    gemm_tiled<100, 50, 64, 112, 64, true, false><<<(n + 63) / 64, 256, 0, stream>>>(
        bufB, W2, dinv, nullptr, bufA, n);
    aggregate<50, 64, 16, false, true><<<(n + 15) / 16, 256, 0, stream>>>(
        bufA, offs, csr, dinv, b2, bufB, n);

    // Layer 3: bufA = (bufB@W3)*dinv (stride 32); bufB = relu(dinv*agg(bufA)+b3) (stride 32)
    gemm_tiled<50, 25, 144, 64, 32, true, false><<<(n + 143) / 144, 256, 0, stream>>>(
        bufB, W3, dinv, nullptr, bufA, n);
    aggregate<25, 32, 8, false, true><<<(n + 31) / 32, 256, 0, stream>>>(
        bufA, offs, csr, dinv, b3, bufB, n);

    // fused MLP head (input stride 32)
    mlp3<<<nb, 256, 0, stream>>>(bufB, Wl1, bl1, Wl2, bl2, Wl3, bl3, (float*)d_out, n);
}

// Round 7
// 361.615 us; speedup vs baseline: 2.3649x; 1.0884x over previous
//
#include <hip/hip_runtime.h>
#include <cstdint>

constexpr int BSHIFT = 9;               // 512 nodes per bucket
constexpr int NBUCK  = 256;             // max buckets (covers 131072 nodes)
constexpr int BUCKET_CAP = 6144;        // slot capacity; E/bucket ~ Poisson(5102), 14 sigma

__device__ __forceinline__ float4 add4(float4 a, float4 b) {
    return make_float4(a.x + b.x, a.y + b.y, a.z + b.z, a.w + b.w);
}
__device__ __forceinline__ float4 mul4s(float4 a, float s) {
    return make_float4(a.x * s, a.y * s, a.z * s, a.w * s);
}

// ---------------- CSR build (bucketed, LDS-local) ----------------

__global__ void zero_ints(int* __restrict__ p, int n) {
    int i = blockIdx.x * blockDim.x + threadIdx.x;
    if (i < n) p[i] = 0;
}

// Bin edges into fixed-capacity bucket slots. Per-block LDS histogram ->
// one global atomic per (block,bucket) -> contiguous run writes.
constexpr int EPT = 16;  // edges per thread; chunk = 4096
__global__ __launch_bounds__(256) void partition_edges(
    const int* __restrict__ src, const int* __restrict__ dst,
    int* __restrict__ bucketCur, int2* __restrict__ pairs, int ne) {
    __shared__ int lcnt[NBUCK];
    __shared__ int lbase[NBUCK];
    int base = blockIdx.x * (256 * EPT);
    if (threadIdx.x < NBUCK) lcnt[threadIdx.x] = 0;
    __syncthreads();
    int2 ed[EPT];
    int  rnk[EPT];
#pragma unroll
    for (int j = 0; j < EPT; ++j) {
        int e = base + j * 256 + threadIdx.x;
        if (e < ne) {
            int d = dst[e];
            ed[j] = make_int2(src[e], d);
            rnk[j] = atomicAdd(&lcnt[d >> BSHIFT], 1);
        } else {
            ed[j].y = -1;
        }
    }
    __syncthreads();
    if (threadIdx.x < NBUCK) {
        int c = lcnt[threadIdx.x];
        lbase[threadIdx.x] = c ? atomicAdd(&bucketCur[threadIdx.x], c) : 0;
    }
    __syncthreads();
#pragma unroll
    for (int j = 0; j < EPT; ++j) {
        if (ed[j].y >= 0) {
            int b = ed[j].y >> BSHIFT;
            int p = lbase[b] + rnk[j];
            if (p < BUCKET_CAP)  // never hit for this input; guards corruption
                pairs[(size_t)b * BUCKET_CAP + p] = ed[j];
        }
    }
}

// Exclusive scan of per-bucket totals -> global bucket bases. nbuckets <= 256.
__global__ void scan_buckets(const int* __restrict__ bucketCnt, int* __restrict__ bucketBase,
                             int* __restrict__ offs, int n, int ne, int nbuckets) {
    __shared__ int tmp[256];
    int c = (threadIdx.x < (unsigned)nbuckets) ? bucketCnt[threadIdx.x] : 0;
    tmp[threadIdx.x] = c;
    __syncthreads();
    for (int off = 1; off < 256; off <<= 1) {
        int t = (threadIdx.x >= (unsigned)off) ? tmp[threadIdx.x - off] : 0;
        __syncthreads();
        tmp[threadIdx.x] += t;
        __syncthreads();
    }
    if (threadIdx.x < (unsigned)nbuckets) bucketBase[threadIdx.x] = tmp[threadIdx.x] - c;
    if (threadIdx.x == 0) offs[n] = ne;
}

// One block per bucket: LDS histogram over the bucket's pairs, LDS scan,
// write offs/dinv, then scatter src into the bucket's csr window (L2-local,
// LDS cursors -- no global atomics).
__global__ __launch_bounds__(256) void bucket_csr(
    const int2* __restrict__ pairs, const int* __restrict__ bucketCnt,
    const int* __restrict__ bucketBase, int* __restrict__ offs,
    float* __restrict__ dinv, int* __restrict__ csr, int n) {
    constexpr int BN = 1 << BSHIFT;  // 512
    __shared__ int hist[BN];
    __shared__ int cur[BN];
    __shared__ int tmp[256];
    int b = blockIdx.x;
    int cnt  = bucketCnt[b];
    int base = bucketBase[b];
    const int2* pb = pairs + (size_t)b * BUCKET_CAP;
    int nodeLo = b << BSHIFT;

    hist[threadIdx.x] = 0;
    hist[threadIdx.x + 256] = 0;
    __syncthreads();
    for (int e = threadIdx.x; e < cnt; e += 256)
        atomicAdd(&hist[pb[e].y - nodeLo], 1);
    __syncthreads();

    int l0 = 2 * threadIdx.x, l1 = l0 + 1;
    int h0 = hist[l0], h1 = hist[l1];
    tmp[threadIdx.x] = h0 + h1;
    __syncthreads();
    for (int off = 1; off < 256; off <<= 1) {
        int t = (threadIdx.x >= (unsigned)off) ? tmp[threadIdx.x - off] : 0;
        __syncthreads();
        tmp[threadIdx.x] += t;
        __syncthreads();
    }
    int e0 = tmp[threadIdx.x] - (h0 + h1);   // exclusive prefix for node l0
    int e1 = e0 + h0;                        // exclusive prefix for node l1
    int g0 = nodeLo + l0, g1 = nodeLo + l1;
    if (g0 < n) { offs[g0] = base + e0; dinv[g0] = rsqrtf((float)(h0 + 1)); }
    if (g1 < n) { offs[g1] = base + e1; dinv[g1] = rsqrtf((float)(h1 + 1)); }
    cur[l0] = e0;
    cur[l1] = e1;
    __syncthreads();

    for (int e = threadIdx.x; e < cnt; e += 256) {
        int2 p = pb[e];
        int pos = atomicAdd(&cur[p.y - nodeLo], 1);
        csr[base + pos] = p.x;
    }
}

// ---------------- aggregation: float4/lane, LPN lanes per node, unroll 8 ----------------
template <int M, int S, int LPN, bool SCALE_SRC, bool RELU_BIAS>
__global__ __launch_bounds__(256) void aggregate(
    const float* __restrict__ s, const int* __restrict__ offs,
    const int* __restrict__ csr, const float* __restrict__ dinv,
    const float* __restrict__ b, float* __restrict__ out, int n) {
    int lane = threadIdx.x % LPN;
    int node = blockIdx.x * (256 / LPN) + threadIdx.x / LPN;
    if (node >= n) return;
    int f0 = lane * 4;
    bool active = f0 < M;
    float dv = dinv[node];

    float4 z = make_float4(0.f, 0.f, 0.f, 0.f);
    float4 acc0 = z, acc1 = z, acc2 = z, acc3 = z;
    if (active) {
        float4 sv = *(const float4*)&s[(size_t)node * S + f0];
        acc0 = SCALE_SRC ? mul4s(sv, dv) : sv;
    }

    int e0 = offs[node], e1 = offs[node + 1];
    int e = e0;
    for (; e + 8 <= e1; e += 8) {
        int id[8];
#pragma unroll
        for (int j = 0; j < 8; ++j) id[j] = csr[e + j];
        float4 v[8];
#pragma unroll
        for (int j = 0; j < 8; ++j)
            v[j] = active ? *(const float4*)&s[(size_t)id[j] * S + f0] : z;
        if (SCALE_SRC) {
#pragma unroll
            for (int j = 0; j < 8; ++j) v[j] = mul4s(v[j], dinv[id[j]]);
        }
        acc0 = add4(acc0, add4(v[0], v[4]));
        acc1 = add4(acc1, add4(v[1], v[5]));
        acc2 = add4(acc2, add4(v[2], v[6]));
        acc3 = add4(acc3, add4(v[3], v[7]));
    }
    for (; e + 4 <= e1; e += 4) {
        int i0 = csr[e], i1 = csr[e + 1], i2 = csr[e + 2], i3 = csr[e + 3];
        float4 v0 = z, v1 = z, v2 = z, v3 = z;
        if (active) {
            v0 = *(const float4*)&s[(size_t)i0 * S + f0];
            v1 = *(const float4*)&s[(size_t)i1 * S + f0];
            v2 = *(const float4*)&s[(size_t)i2 * S + f0];
            v3 = *(const float4*)&s[(size_t)i3 * S + f0];
        }
        if (SCALE_SRC) {
            v0 = mul4s(v0, dinv[i0]); v1 = mul4s(v1, dinv[i1]);
            v2 = mul4s(v2, dinv[i2]); v3 = mul4s(v3, dinv[i3]);
        }
        acc0 = add4(acc0, v0); acc1 = add4(acc1, v1);
        acc2 = add4(acc2, v2); acc3 = add4(acc3, v3);
    }
    for (; e < e1; ++e) {
        int sid = csr[e];
        float4 v = active ? *(const float4*)&s[(size_t)sid * S + f0] : z;
        if (SCALE_SRC) v = mul4s(v, dinv[sid]);
        acc0 = add4(acc0, v);
    }
    float4 acc = add4(add4(acc0, acc1), add4(acc2, acc3));

    if (active) {
        float4 r = mul4s(acc, dv);
        if (RELU_BIAS) {
            if (f0 + 0 < M) r.x = fmaxf(r.x + b[f0 + 0], 0.0f);
            if (f0 + 1 < M) r.y = fmaxf(r.y + b[f0 + 1], 0.0f);
            if (f0 + 2 < M) r.z = fmaxf(r.z + b[f0 + 2], 0.0f);
            if (f0 + 3 < M) r.w = fmaxf(r.w + b[f0 + 3], 0.0f);
        }
        float* o = &out[(size_t)node * S + f0];
        if (f0 + 3 < M) {
            *(float4*)o = r;
        } else {
            if (f0 + 0 < M) o[0] = r.x;
            if (f0 + 1 < M) o[1] = r.y;
            if (f0 + 2 < M) o[2] = r.z;
            if (f0 + 3 < M) o[3] = r.w;
        }
    }
}

// ---------------- register-tiled GEMM, conflict-free node-fast staging ----------------
template <int K, int M, int NT, int XS, int OS, bool SCALE, bool BIAS_RELU>
__global__ __launch_bounds__(256) void gemm_tiled(
    const float* __restrict__ x, const float* __restrict__ W,
    const float* __restrict__ dinv, const float* __restrict__ b,
    float* __restrict__ out, int n) {
    static_assert(NT % 4 == 0 && K % 2 == 0 && XS % 16 == 0 && OS % 4 == 0, "");
    constexpr int Mp  = (M + 3) & ~3;
    constexpr int MQ  = Mp / 4;
    constexpr int NTp = NT + 4;
    constexpr int NTILES = (NT / 4) * MQ;
    static_assert(NTILES <= 256, "");

    __shared__ float Xs[K * NTp];
    __shared__ float Ws[K * Mp];

    if constexpr (M % 4 == 0) {
        for (int i = threadIdx.x; i < K * M / 4; i += 256)
            ((float4*)Ws)[i] = ((const float4*)W)[i];
    } else if constexpr (M % 2 == 0) {
        constexpr int C2 = Mp / 2;
        for (int i = threadIdx.x; i < K * C2; i += 256) {
            int r = i / C2, c = i - r * C2;
            float2 v;
            if (c * 2 + 1 < M)      v = *(const float2*)&W[r * M + c * 2];
            else if (c * 2 < M)     v = make_float2(W[r * M + c * 2], 0.0f);
            else                    v = make_float2(0.0f, 0.0f);
            *(float2*)&Ws[r * Mp + c * 2] = v;
        }
    } else {
        for (int i = threadIdx.x; i < K * Mp; i += 256) {
            int r = i / Mp, c = i - r * Mp;
            Ws[i] = (c < M) ? W[r * M + c] : 0.0f;
        }
    }

    int nodeBase = blockIdx.x * NT;
    constexpr int KV = (K % 4 == 0) ? 4 : 2;
    for (int it = threadIdx.x; it < NT * (K / KV); it += 256) {
        int node = it % NT;
        int kv = it / NT;
        int gn = nodeBase + node;
        if constexpr (KV == 4) {
            float4 v = make_float4(0.f, 0.f, 0.f, 0.f);
            if (gn < n) v = *(const float4*)&x[(size_t)gn * XS + kv * 4];
            Xs[(kv * 4 + 0) * NTp + node] = v.x;
            Xs[(kv * 4 + 1) * NTp + node] = v.y;
            Xs[(kv * 4 + 2) * NTp + node] = v.z;
            Xs[(kv * 4 + 3) * NTp + node] = v.w;
        } else {
            float2 v = make_float2(0.f, 0.f);
            if (gn < n) v = *(const float2*)&x[(size_t)gn * XS + kv * 2];
            Xs[(kv * 2 + 0) * NTp + node] = v.x;
            Xs[(kv * 2 + 1) * NTp + node] = v.y;
        }
    }
    __syncthreads();

    int t = threadIdx.x;
    if (t >= NTILES) return;
    int ng = t / MQ, mq = t - ng * MQ;
    int n0 = ng * 4;
    int m0 = mq * 4;

    float acc[4][4];
#pragma unroll
    for (int j = 0; j < 4; ++j)
#pragma unroll
        for (int i = 0; i < 4; ++i) acc[j][i] = 0.0f;

#pragma unroll 4
    for (int k = 0; k < K; ++k) {
        float4 xv = *(const float4*)&Xs[k * NTp + n0];
        float4 wv = *(const float4*)&Ws[k * Mp + m0];
        acc[0][0] = fmaf(xv.x, wv.x, acc[0][0]);
        acc[0][1] = fmaf(xv.x, wv.y, acc[0][1]);
        acc[0][2] = fmaf(xv.x, wv.z, acc[0][2]);
        acc[0][3] = fmaf(xv.x, wv.w, acc[0][3]);
        acc[1][0] = fmaf(xv.y, wv.x, acc[1][0]);
        acc[1][1] = fmaf(xv.y, wv.y, acc[1][1]);
        acc[1][2] = fmaf(xv.y, wv.z, acc[1][2]);
        acc[1][3] = fmaf(xv.y, wv.w, acc[1][3]);
        acc[2][0] = fmaf(xv.z, wv.x, acc[2][0]);
        acc[2][1] = fmaf(xv.z, wv.y, acc[2][1]);
        acc[2][2] = fmaf(xv.z, wv.z, acc[2][2]);
        acc[2][3] = fmaf(xv.z, wv.w, acc[2][3]);
        acc[3][0] = fmaf(xv.w, wv.x, acc[3][0]);
        acc[3][1] = fmaf(xv.w, wv.y, acc[3][1]);
        acc[3][2] = fmaf(xv.w, wv.z, acc[3][2]);
        acc[3][3] = fmaf(xv.w, wv.w, acc[3][3]);
    }

#pragma unroll
    for (int j = 0; j < 4; ++j) {
        int nd = nodeBase + n0 + j;
        if (nd >= n) continue;
        float dv = SCALE ? dinv[nd] : 1.0f;
        if (m0 + 3 < M) {
            float4 r = make_float4(acc[j][0], acc[j][1], acc[j][2], acc[j][3]);
            if (SCALE) r = mul4s(r, dv);
            if (BIAS_RELU) {
                r.x = fmaxf(r.x + b[m0 + 0], 0.0f);
                r.y = fmaxf(r.y + b[m0 + 1], 0.0f);
                r.z = fmaxf(r.z + b[m0 + 2], 0.0f);
                r.w = fmaxf(r.w + b[m0 + 3], 0.0f);
            }
            *(float4*)&out[(size_t)nd * OS + m0] = r;
        } else {
#pragma unroll
            for (int i = 0; i < 4; ++i) {
                int m = m0 + i;
                if (m < M) {
                    float r = acc[j][i];
                    if (SCALE) r *= dv;
                    if (BIAS_RELU) r = fmaxf(r + b[m], 0.0f);
                    out[(size_t)nd * OS + m] = r;
                }
            }
        }
    }
}

// ---------------- fused 3-layer MLP: 25 -> 25 -> 10 -> 1 (input stride 32) ----------------

__global__ void mlp3(const float* __restrict__ x,
                     const float* __restrict__ Wl1, const float* __restrict__ bl1,
                     const float* __restrict__ Wl2, const float* __restrict__ bl2,
                     const float* __restrict__ Wl3, const float* __restrict__ bl3,
                     float* __restrict__ out, int n) {
    __shared__ float W1s[25 * 25], W2s[25 * 10], W3s[10], b1s[25], b2s[10], b3s;
    for (int i = threadIdx.x; i < 625; i += blockDim.x) W1s[i] = Wl1[i];
    for (int i = threadIdx.x; i < 250; i += blockDim.x) W2s[i] = Wl2[i];
    if (threadIdx.x < 10) { W3s[threadIdx.x] = Wl3[threadIdx.x]; b2s[threadIdx.x] = bl2[threadIdx.x]; }
    if (threadIdx.x < 25) b1s[threadIdx.x] = bl1[threadIdx.x];
    if (threadIdx.x == 0) b3s = bl3[0];
    __syncthreads();
    int node = blockIdx.x * blockDim.x + threadIdx.x;
    if (node >= n) return;
    float xr[25];
#pragma unroll
    for (int k = 0; k < 25; ++k) xr[k] = x[(size_t)node * 32 + k];
    float h1[25];
#pragma unroll
    for (int m = 0; m < 25; ++m) {
        float a = b1s[m];
#pragma unroll
        for (int k = 0; k < 25; ++k) a = fmaf(xr[k], W1s[k * 25 + m], a);
        h1[m] = fmaxf(a, 0.0f);
    }
    float h2[10];
#pragma unroll
    for (int m = 0; m < 10; ++m) {
        float a = b2s[m];
#pragma unroll
        for (int k = 0; k < 25; ++k) a = fmaf(h1[k], W2s[k * 10 + m], a);
        h2[m] = fmaxf(a, 0.0f);
    }
    float a = b3s;
#pragma unroll
    for (int k = 0; k < 10; ++k) a = fmaf(h2[k], W3s[k], a);
    out[node] = fmaxf(a, 0.0f);
}

// ---------------- launch ----------------

extern "C" void kernel_launch(void* const* d_in, const int* in_sizes, int n_in,
                              void* d_out, int out_size, void* d_ws, size_t ws_size,
                              hipStream_t stream) {
    const float* x0  = (const float*)d_in[0];
    const float* W1  = (const float*)d_in[1];
    const float* b1  = (const float*)d_in[2];
    const float* W2  = (const float*)d_in[3];
    const float* b2  = (const float*)d_in[4];
    const float* W3  = (const float*)d_in[5];
    const float* b3  = (const float*)d_in[6];
    const float* Wl1 = (const float*)d_in[7];
    const float* bl1 = (const float*)d_in[8];
    const float* Wl2 = (const float*)d_in[9];
    const float* bl2 = (const float*)d_in[10];
    const float* Wl3 = (const float*)d_in[11];
    const float* bl3 = (const float*)d_in[12];
    const int*   edge = (const int*)d_in[13];

    int n  = in_sizes[0] / 64;      // 100000
    int ne = in_sizes[13] / 2;      // 1000000
    const int* esrc = edge;
    const int* edst = edge + ne;

    char* ws = (char*)d_ws;
    auto alloc = [&](size_t bytes) {
        char* p = ws;
        ws += (bytes + 255) & ~(size_t)255;
        return p;
    };
    int*   offs       = (int*)alloc((size_t)(n + 1) * 4);
    int*   bucketCur  = (int*)alloc(NBUCK * 4);
    int*   bucketBase = (int*)alloc(NBUCK * 4);
    int*   csr        = (int*)alloc((size_t)ne * 4);
    float* dinv       = (float*)alloc((size_t)n * 4);
    float* bufA       = (float*)alloc((size_t)n * 64 * 4);    // stride-64 buffer
    float* bufB       = (float*)alloc((size_t)n * 112 * 4);   // stride-112 buffer
    int2*  pairs      = (int2*)bufA;   // 196*6144*8 = 9.6MB, consumed before aggregate1 writes bufA
    (void)ws_size; (void)n_in; (void)out_size;

    int nb = (n + 255) / 256;
    int nbuckets = (n + (1 << BSHIFT) - 1) >> BSHIFT;   // 196

    // CSR + dinv (4 dispatches)
    zero_ints<<<1, 256, 0, stream>>>(bucketCur, NBUCK);
    partition_edges<<<(ne + 256 * EPT - 1) / (256 * EPT), 256, 0, stream>>>(
        esrc, edst, bucketCur, pairs, ne);
    scan_buckets<<<1, 256, 0, stream>>>(bucketCur, bucketBase, offs, n, ne, nbuckets);
    bucket_csr<<<nbuckets, 256, 0, stream>>>(pairs, bucketCur, bucketBase, offs, dinv, csr, n);

    // Layer 1 (aggregate-first): bufA = ÂX (stride 64); bufB = relu(bufA@W1+b1) (stride 112)
    aggregate<64, 64, 16, true, false><<<(n + 15) / 16, 256, 0, stream>>>(
        x0, offs, csr, dinv, nullptr, bufA, n);
    gemm_tiled<64, 100, 40, 64, 112, false, true><<<(n + 39) / 40, 256, 0, stream>>>(
        bufA, W1, nullptr, b1, bufB, n);

    // Layer 2: bufA = (bufB@W2)*dinv (stride 64); bufB = relu(dinv*agg(bufA)+b2) (stride 64)
    gemm_tiled<100, 50, 64, 112, 64, true, false><<<(n + 63) / 64, 256, 0, stream>>>(
        bufB, W2, dinv, nullptr, bufA, n);
    aggregate<50, 64, 16, false, true><<<(n + 15) / 16, 256, 0, stream>>>(
        bufA, offs, csr, dinv, b2, bufB, n);

    // Layer 3: bufA = (bufB@W3)*dinv (stride 32); bufB = relu(dinv*agg(bufA)+b3) (stride 32)
    gemm_tiled<50, 25, 144, 64, 32, true, false><<<(n + 143) / 144, 256, 0, stream>>>(
        bufB, W3, dinv, nullptr, bufA, n);
    aggregate<25, 32, 8, false, true><<<(n + 31) / 32, 256, 0, stream>>>(
        bufA, offs, csr, dinv, b3, bufB, n);

    // fused MLP head (input stride 32)
    mlp3<<<nb, 256, 0, stream>>>(bufB, Wl1, bl1, Wl2, bl2, Wl3, bl3, (float*)d_out, n);
}

// Round 8
// 329.805 us; speedup vs baseline: 2.5930x; 1.0965x over previous
//
#include <hip/hip_runtime.h>
#include <cstdint>

constexpr int BSHIFT = 9;               // 512 nodes per bucket
constexpr int NBUCK  = 256;             // max buckets (covers 131072 nodes)
constexpr int BUCKET_CAP = 6144;        // slot capacity; E/bucket ~ Poisson(5102), 14 sigma

__device__ __forceinline__ float4 add4(float4 a, float4 b) {
    return make_float4(a.x + b.x, a.y + b.y, a.z + b.z, a.w + b.w);
}
__device__ __forceinline__ float4 mul4s(float4 a, float s) {
    return make_float4(a.x * s, a.y * s, a.z * s, a.w * s);
}

// ---------------- CSR build (bucketed, LDS-local) ----------------

__global__ void zero_ints(int* __restrict__ p, int n) {
    int i = blockIdx.x * blockDim.x + threadIdx.x;
    if (i < n) p[i] = 0;
}

constexpr int EPT = 16;  // edges per thread; chunk = 4096
__global__ __launch_bounds__(256) void partition_edges(
    const int* __restrict__ src, const int* __restrict__ dst,
    int* __restrict__ bucketCur, int2* __restrict__ pairs, int ne) {
    __shared__ int lcnt[NBUCK];
    __shared__ int lbase[NBUCK];
    int base = blockIdx.x * (256 * EPT);
    if (threadIdx.x < NBUCK) lcnt[threadIdx.x] = 0;
    __syncthreads();
    int2 ed[EPT];
    int  rnk[EPT];
#pragma unroll
    for (int j = 0; j < EPT; ++j) {
        int e = base + j * 256 + threadIdx.x;
        if (e < ne) {
            int d = dst[e];
            ed[j] = make_int2(src[e], d);
            rnk[j] = atomicAdd(&lcnt[d >> BSHIFT], 1);
        } else {
            ed[j].y = -1;
        }
    }
    __syncthreads();
    if (threadIdx.x < NBUCK) {
        int c = lcnt[threadIdx.x];
        lbase[threadIdx.x] = c ? atomicAdd(&bucketCur[threadIdx.x], c) : 0;
    }
    __syncthreads();
#pragma unroll
    for (int j = 0; j < EPT; ++j) {
        if (ed[j].y >= 0) {
            int b = ed[j].y >> BSHIFT;
            int p = lbase[b] + rnk[j];
            if (p < BUCKET_CAP)  // never hit for this input; guards corruption
                pairs[(size_t)b * BUCKET_CAP + p] = ed[j];
        }
    }
}

__global__ void scan_buckets(const int* __restrict__ bucketCnt, int* __restrict__ bucketBase,
                             int* __restrict__ offs, int n, int ne, int nbuckets) {
    __shared__ int tmp[256];
    int c = (threadIdx.x < (unsigned)nbuckets) ? bucketCnt[threadIdx.x] : 0;
    tmp[threadIdx.x] = c;
    __syncthreads();
    for (int off = 1; off < 256; off <<= 1) {
        int t = (threadIdx.x >= (unsigned)off) ? tmp[threadIdx.x - off] : 0;
        __syncthreads();
        tmp[threadIdx.x] += t;
        __syncthreads();
    }
    if (threadIdx.x < (unsigned)nbuckets) bucketBase[threadIdx.x] = tmp[threadIdx.x] - c;
    if (threadIdx.x == 0) offs[n] = ne;
}

__global__ __launch_bounds__(256) void bucket_csr(
    const int2* __restrict__ pairs, const int* __restrict__ bucketCnt,
    const int* __restrict__ bucketBase, int* __restrict__ offs,
    float* __restrict__ dinv, int* __restrict__ csr, int n) {
    constexpr int BN = 1 << BSHIFT;  // 512
    __shared__ int hist[BN];
    __shared__ int cur[BN];
    __shared__ int tmp[256];
    int b = blockIdx.x;
    int cnt  = bucketCnt[b];
    int base = bucketBase[b];
    const int2* pb = pairs + (size_t)b * BUCKET_CAP;
    int nodeLo = b << BSHIFT;

    hist[threadIdx.x] = 0;
    hist[threadIdx.x + 256] = 0;
    __syncthreads();
    for (int e = threadIdx.x; e < cnt; e += 256)
        atomicAdd(&hist[pb[e].y - nodeLo], 1);
    __syncthreads();

    int l0 = 2 * threadIdx.x, l1 = l0 + 1;
    int h0 = hist[l0], h1 = hist[l1];
    tmp[threadIdx.x] = h0 + h1;
    __syncthreads();
    for (int off = 1; off < 256; off <<= 1) {
        int t = (threadIdx.x >= (unsigned)off) ? tmp[threadIdx.x - off] : 0;
        __syncthreads();
        tmp[threadIdx.x] += t;
        __syncthreads();
    }
    int e0 = tmp[threadIdx.x] - (h0 + h1);
    int e1 = e0 + h0;
    int g0 = nodeLo + l0, g1 = nodeLo + l1;
    if (g0 < n) { offs[g0] = base + e0; dinv[g0] = rsqrtf((float)(h0 + 1)); }
    if (g1 < n) { offs[g1] = base + e1; dinv[g1] = rsqrtf((float)(h1 + 1)); }
    cur[l0] = e0;
    cur[l1] = e1;
    __syncthreads();

    for (int e = threadIdx.x; e < cnt; e += 256) {
        int2 p = pb[e];
        int pos = atomicAdd(&cur[p.y - nodeLo], 1);
        csr[base + pos] = p.x;
    }
}

// ---------------- aggregation: float4/lane, LPN lanes per node, unroll 4 ----------------
// (R5 form: unroll-8 measured SLOWER -- 36 VGPR, coarser waitcnt batching; keep 4.)
template <int M, int S, int LPN, bool SCALE_SRC, bool RELU_BIAS>
__global__ __launch_bounds__(256) void aggregate(
    const float* __restrict__ s, const int* __restrict__ offs,
    const int* __restrict__ csr, const float* __restrict__ dinv,
    const float* __restrict__ b, float* __restrict__ out, int n) {
    int lane = threadIdx.x % LPN;
    int node = blockIdx.x * (256 / LPN) + threadIdx.x / LPN;
    if (node >= n) return;
    int f0 = lane * 4;
    bool active = f0 < M;
    float dv = dinv[node];

    float4 z = make_float4(0.f, 0.f, 0.f, 0.f);
    float4 acc0 = z, acc1 = z, acc2 = z, acc3 = z;
    if (active) {
        float4 sv = *(const float4*)&s[(size_t)node * S + f0];
        acc0 = SCALE_SRC ? mul4s(sv, dv) : sv;
    }

    int e0 = offs[node], e1 = offs[node + 1];
    int e = e0;
    for (; e + 4 <= e1; e += 4) {
        int i0 = csr[e], i1 = csr[e + 1], i2 = csr[e + 2], i3 = csr[e + 3];
        float4 v0 = z, v1 = z, v2 = z, v3 = z;
        if (active) {
            v0 = *(const float4*)&s[(size_t)i0 * S + f0];
            v1 = *(const float4*)&s[(size_t)i1 * S + f0];
            v2 = *(const float4*)&s[(size_t)i2 * S + f0];
            v3 = *(const float4*)&s[(size_t)i3 * S + f0];
        }
        if (SCALE_SRC) {
            v0 = mul4s(v0, dinv[i0]); v1 = mul4s(v1, dinv[i1]);
            v2 = mul4s(v2, dinv[i2]); v3 = mul4s(v3, dinv[i3]);
        }
        acc0 = add4(acc0, v0); acc1 = add4(acc1, v1);
        acc2 = add4(acc2, v2); acc3 = add4(acc3, v3);
    }
    for (; e < e1; ++e) {
        int sid = csr[e];
        float4 v = active ? *(const float4*)&s[(size_t)sid * S + f0] : z;
        if (SCALE_SRC) v = mul4s(v, dinv[sid]);
        acc0 = add4(acc0, v);
    }
    float4 acc = add4(add4(acc0, acc1), add4(acc2, acc3));

    if (active) {
        float4 r = mul4s(acc, dv);
        if (RELU_BIAS) {
            if (f0 + 0 < M) r.x = fmaxf(r.x + b[f0 + 0], 0.0f);
            if (f0 + 1 < M) r.y = fmaxf(r.y + b[f0 + 1], 0.0f);
            if (f0 + 2 < M) r.z = fmaxf(r.z + b[f0 + 2], 0.0f);
            if (f0 + 3 < M) r.w = fmaxf(r.w + b[f0 + 3], 0.0f);
        }
        float* o = &out[(size_t)node * S + f0];
        if (f0 + 3 < M) {
            *(float4*)o = r;
        } else {
            if (f0 + 0 < M) o[0] = r.x;
            if (f0 + 1 < M) o[1] = r.y;
            if (f0 + 2 < M) o[2] = r.z;
            if (f0 + 3 < M) o[3] = r.w;
        }
    }
}

// ---------------- fused layer-3 aggregate + 3-layer MLP head ----------------
// Phase A: aggregate (M=25, S=32, LPN=8, unroll-4) -> LDS acc (32 nodes/block).
// Phase B: 32 threads run 25->25->10->1 MLP from LDS, write d_out.
__global__ __launch_bounds__(256) void agg3_mlp(
    const float* __restrict__ s, const int* __restrict__ offs,
    const int* __restrict__ csr, const float* __restrict__ dinv,
    const float* __restrict__ bg,   // GCN layer-3 bias (25)
    const float* __restrict__ Wl1, const float* __restrict__ bl1,
    const float* __restrict__ Wl2, const float* __restrict__ bl2,
    const float* __restrict__ Wl3, const float* __restrict__ bl3,
    float* __restrict__ out, int n) {
    constexpr int M = 25, S = 32, LPN = 8;
    __shared__ float W1s[625], W2s[250], W3s[10], b1s[25], b2s[10];
    __shared__ float accs[32 * 26];   // stride 26: 2-way banks max on phase-B reads
    __shared__ float b3s;

    for (int i = threadIdx.x; i < 625; i += 256) W1s[i] = Wl1[i];
    for (int i = threadIdx.x; i < 250; i += 256) W2s[i] = Wl2[i];
    if (threadIdx.x < 10) { W3s[threadIdx.x] = Wl3[threadIdx.x]; b2s[threadIdx.x] = bl2[threadIdx.x]; }
    if (threadIdx.x < 25) b1s[threadIdx.x] = bl1[threadIdx.x];
    if (threadIdx.x == 0) b3s = bl3[0];

    int lane = threadIdx.x % LPN;
    int nl   = threadIdx.x / LPN;
    int node = blockIdx.x * 32 + nl;
    int f0 = lane * 4;

    if (node < n) {
        bool active = f0 < M;
        float dv = dinv[node];
        float4 z = make_float4(0.f, 0.f, 0.f, 0.f);
        float4 acc0 = z, acc1 = z, acc2 = z, acc3 = z;
        if (active) acc0 = *(const float4*)&s[(size_t)node * S + f0];

        int e0 = offs[node], e1 = offs[node + 1];
        int e = e0;
        for (; e + 4 <= e1; e += 4) {
            int i0 = csr[e], i1 = csr[e + 1], i2 = csr[e + 2], i3 = csr[e + 3];
            float4 v0 = z, v1 = z, v2 = z, v3 = z;
            if (active) {
                v0 = *(const float4*)&s[(size_t)i0 * S + f0];
                v1 = *(const float4*)&s[(size_t)i1 * S + f0];
                v2 = *(const float4*)&s[(size_t)i2 * S + f0];
                v3 = *(const float4*)&s[(size_t)i3 * S + f0];
            }
            acc0 = add4(acc0, v0); acc1 = add4(acc1, v1);
            acc2 = add4(acc2, v2); acc3 = add4(acc3, v3);
        }
        for (; e < e1; ++e) {
            int sid = csr[e];
            float4 v = active ? *(const float4*)&s[(size_t)sid * S + f0] : z;
            acc0 = add4(acc0, v);
        }
        float4 acc = add4(add4(acc0, acc1), add4(acc2, acc3));

        if (active) {
            float4 r = mul4s(acc, dv);
            if (f0 + 0 < M) accs[nl * 26 + f0 + 0] = fmaxf(r.x + bg[f0 + 0], 0.0f);
            if (f0 + 1 < M) accs[nl * 26 + f0 + 1] = fmaxf(r.y + bg[f0 + 1], 0.0f);
            if (f0 + 2 < M) accs[nl * 26 + f0 + 2] = fmaxf(r.z + bg[f0 + 2], 0.0f);
            if (f0 + 3 < M) accs[nl * 26 + f0 + 3] = fmaxf(r.w + bg[f0 + 3], 0.0f);
        }
    }
    __syncthreads();

    if (threadIdx.x < 32) {
        int nd = blockIdx.x * 32 + threadIdx.x;
        if (nd < n) {
            const float* xr = &accs[threadIdx.x * 26];
            float h1[25];
#pragma unroll
            for (int m = 0; m < 25; ++m) {
                float a = b1s[m];
#pragma unroll
                for (int k = 0; k < 25; ++k) a = fmaf(xr[k], W1s[k * 25 + m], a);
                h1[m] = fmaxf(a, 0.0f);
            }
            float h2[10];
#pragma unroll
            for (int m = 0; m < 10; ++m) {
                float a = b2s[m];
#pragma unroll
                for (int k = 0; k < 25; ++k) a = fmaf(h1[k], W2s[k * 10 + m], a);
                h2[m] = fmaxf(a, 0.0f);
            }
            float a = b3s;
#pragma unroll
            for (int k = 0; k < 10; ++k) a = fmaf(h2[k], W3s[k], a);
            out[nd] = fmaxf(a, 0.0f);
        }
    }
}

// ---------------- register-tiled GEMM, conflict-free node-fast staging ----------------
template <int K, int M, int NT, int XS, int OS, bool SCALE, bool BIAS_RELU>
__global__ __launch_bounds__(256) void gemm_tiled(
    const float* __restrict__ x, const float* __restrict__ W,
    const float* __restrict__ dinv, const float* __restrict__ b,
    float* __restrict__ out, int n) {
    static_assert(NT % 4 == 0 && K % 2 == 0 && XS % 16 == 0 && OS % 4 == 0, "");
    constexpr int Mp  = (M + 3) & ~3;
    constexpr int MQ  = Mp / 4;
    constexpr int NTp = NT + 4;
    constexpr int NTILES = (NT / 4) * MQ;
    static_assert(NTILES <= 256, "");

    __shared__ float Xs[K * NTp];
    __shared__ float Ws[K * Mp];

    if constexpr (M % 4 == 0) {
        for (int i = threadIdx.x; i < K * M / 4; i += 256)
            ((float4*)Ws)[i] = ((const float4*)W)[i];
    } else if constexpr (M % 2 == 0) {
        constexpr int C2 = Mp / 2;
        for (int i = threadIdx.x; i < K * C2; i += 256) {
            int r = i / C2, c = i - r * C2;
            float2 v;
            if (c * 2 + 1 < M)      v = *(const float2*)&W[r * M + c * 2];
            else if (c * 2 < M)     v = make_float2(W[r * M + c * 2], 0.0f);
            else                    v = make_float2(0.0f, 0.0f);
            *(float2*)&Ws[r * Mp + c * 2] = v;
        }
    } else {
        for (int i = threadIdx.x; i < K * Mp; i += 256) {
            int r = i / Mp, c = i - r * Mp;
            Ws[i] = (c < M) ? W[r * M + c] : 0.0f;
        }
    }

    int nodeBase = blockIdx.x * NT;
    constexpr int KV = (K % 4 == 0) ? 4 : 2;
    for (int it = threadIdx.x; it < NT * (K / KV); it += 256) {
        int node = it % NT;
        int kv = it / NT;
        int gn = nodeBase + node;
        if constexpr (KV == 4) {
            float4 v = make_float4(0.f, 0.f, 0.f, 0.f);
            if (gn < n) v = *(const float4*)&x[(size_t)gn * XS + kv * 4];
            Xs[(kv * 4 + 0) * NTp + node] = v.x;
            Xs[(kv * 4 + 1) * NTp + node] = v.y;
            Xs[(kv * 4 + 2) * NTp + node] = v.z;
            Xs[(kv * 4 + 3) * NTp + node] = v.w;
        } else {
            float2 v = make_float2(0.f, 0.f);
            if (gn < n) v = *(const float2*)&x[(size_t)gn * XS + kv * 2];
            Xs[(kv * 2 + 0) * NTp + node] = v.x;
            Xs[(kv * 2 + 1) * NTp + node] = v.y;
        }
    }
    __syncthreads();

    int t = threadIdx.x;
    if (t >= NTILES) return;
    int ng = t / MQ, mq = t - ng * MQ;
    int n0 = ng * 4;
    int m0 = mq * 4;

    float acc[4][4];
#pragma unroll
    for (int j = 0; j < 4; ++j)
#pragma unroll
        for (int i = 0; i < 4; ++i) acc[j][i] = 0.0f;

#pragma unroll 4
    for (int k = 0; k < K; ++k) {
        float4 xv = *(const float4*)&Xs[k * NTp + n0];
        float4 wv = *(const float4*)&Ws[k * Mp + m0];
        acc[0][0] = fmaf(xv.x, wv.x, acc[0][0]);
        acc[0][1] = fmaf(xv.x, wv.y, acc[0][1]);
        acc[0][2] = fmaf(xv.x, wv.z, acc[0][2]);
        acc[0][3] = fmaf(xv.x, wv.w, acc[0][3]);
        acc[1][0] = fmaf(xv.y, wv.x, acc[1][0]);
        acc[1][1] = fmaf(xv.y, wv.y, acc[1][1]);
        acc[1][2] = fmaf(xv.y, wv.z, acc[1][2]);
        acc[1][3] = fmaf(xv.y, wv.w, acc[1][3]);
        acc[2][0] = fmaf(xv.z, wv.x, acc[2][0]);
        acc[2][1] = fmaf(xv.z, wv.y, acc[2][1]);
        acc[2][2] = fmaf(xv.z, wv.z, acc[2][2]);
        acc[2][3] = fmaf(xv.z, wv.w, acc[2][3]);
        acc[3][0] = fmaf(xv.w, wv.x, acc[3][0]);
        acc[3][1] = fmaf(xv.w, wv.y, acc[3][1]);
        acc[3][2] = fmaf(xv.w, wv.z, acc[3][2]);
        acc[3][3] = fmaf(xv.w, wv.w, acc[3][3]);
    }

#pragma unroll
    for (int j = 0; j < 4; ++j) {
        int nd = nodeBase + n0 + j;
        if (nd >= n) continue;
        float dv = SCALE ? dinv[nd] : 1.0f;
        if (m0 + 3 < M) {
            float4 r = make_float4(acc[j][0], acc[j][1], acc[j][2], acc[j][3]);
            if (SCALE) r = mul4s(r, dv);
            if (BIAS_RELU) {
                r.x = fmaxf(r.x + b[m0 + 0], 0.0f);
                r.y = fmaxf(r.y + b[m0 + 1], 0.0f);
                r.z = fmaxf(r.z + b[m0 + 2], 0.0f);
                r.w = fmaxf(r.w + b[m0 + 3], 0.0f);
            }
            *(float4*)&out[(size_t)nd * OS + m0] = r;
        } else {
#pragma unroll
            for (int i = 0; i < 4; ++i) {
                int m = m0 + i;
                if (m < M) {
                    float r = acc[j][i];
                    if (SCALE) r *= dv;
                    if (BIAS_RELU) r = fmaxf(r + b[m], 0.0f);
                    out[(size_t)nd * OS + m] = r;
                }
            }
        }
    }
}

// ---------------- launch ----------------

extern "C" void kernel_launch(void* const* d_in, const int* in_sizes, int n_in,
                              void* d_out, int out_size, void* d_ws, size_t ws_size,
                              hipStream_t stream) {
    const float* x0  = (const float*)d_in[0];
    const float* W1  = (const float*)d_in[1];
    const float* b1  = (const float*)d_in[2];
    const float* W2  = (const float*)d_in[3];
    const float* b2  = (const float*)d_in[4];
    const float* W3  = (const float*)d_in[5];
    const float* b3  = (const float*)d_in[6];
    const float* Wl1 = (const float*)d_in[7];
    const float* bl1 = (const float*)d_in[8];
    const float* Wl2 = (const float*)d_in[9];
    const float* bl2 = (const float*)d_in[10];
    const float* Wl3 = (const float*)d_in[11];
    const float* bl3 = (const float*)d_in[12];
    const int*   edge = (const int*)d_in[13];

    int n  = in_sizes[0] / 64;      // 100000
    int ne = in_sizes[13] / 2;      // 1000000
    const int* esrc = edge;
    const int* edst = edge + ne;

    char* ws = (char*)d_ws;
    auto alloc = [&](size_t bytes) {
        char* p = ws;
        ws += (bytes + 255) & ~(size_t)255;
        return p;
    };
    int*   offs       = (int*)alloc((size_t)(n + 1) * 4);
    int*   bucketCur  = (int*)alloc(NBUCK * 4);
    int*   bucketBase = (int*)alloc(NBUCK * 4);
    int*   csr        = (int*)alloc((size_t)ne * 4);
    float* dinv       = (float*)alloc((size_t)n * 4);
    float* bufA       = (float*)alloc((size_t)n * 64 * 4);    // stride-64 buffer
    float* bufB       = (float*)alloc((size_t)n * 112 * 4);   // stride-112 buffer
    int2*  pairs      = (int2*)bufA;   // 9.6MB, consumed before aggregate1 writes bufA
    (void)ws_size; (void)n_in; (void)out_size;

    int nbuckets = (n + (1 << BSHIFT) - 1) >> BSHIFT;   // 196

    // CSR + dinv (4 dispatches)
    zero_ints<<<1, 256, 0, stream>>>(bucketCur, NBUCK);
    partition_edges<<<(ne + 256 * EPT - 1) / (256 * EPT), 256, 0, stream>>>(
        esrc, edst, bucketCur, pairs, ne);
    scan_buckets<<<1, 256, 0, stream>>>(bucketCur, bucketBase, offs, n, ne, nbuckets);
    bucket_csr<<<nbuckets, 256, 0, stream>>>(pairs, bucketCur, bucketBase, offs, dinv, csr, n);

    // Layer 1 (aggregate-first): bufA = ÂX (stride 64); bufB = relu(bufA@W1+b1) (stride 112)
    aggregate<64, 64, 16, true, false><<<(n + 15) / 16, 256, 0, stream>>>(
        x0, offs, csr, dinv, nullptr, bufA, n);
    gemm_tiled<64, 100, 40, 64, 112, false, true><<<(n + 39) / 40, 256, 0, stream>>>(
        bufA, W1, nullptr, b1, bufB, n);

    // Layer 2: bufA = (bufB@W2)*dinv (stride 64); bufB = relu(dinv*agg(bufA)+b2) (stride 64)
    gemm_tiled<100, 50, 64, 112, 64, true, false><<<(n + 63) / 64, 256, 0, stream>>>(
        bufB, W2, dinv, nullptr, bufA, n);
    aggregate<50, 64, 16, false, true><<<(n + 15) / 16, 256, 0, stream>>>(
        bufA, offs, csr, dinv, b2, bufB, n);

    // Layer 3: bufA = (bufB@W3)*dinv (stride 32); fused aggregate+MLP -> d_out
    gemm_tiled<50, 25, 144, 64, 32, true, false><<<(n + 143) / 144, 256, 0, stream>>>(
        bufB, W3, dinv, nullptr, bufA, n);
    agg3_mlp<<<(n + 31) / 32, 256, 0, stream>>>(
        bufA, offs, csr, dinv, b3, Wl1, bl1, Wl2, bl2, Wl3, bl3, (float*)d_out, n);
}